// Round 6
// baseline (1161.340 us; speedup 1.0000x reference)
//
#include <hip/hip_runtime.h>
#include <hip/hip_bf16.h>

#define DIM  1024
#define HID  2816
#define NE   8
#define NTOK 4096
#define NPAIR 8192
#define CAP  8192

typedef __bf16 bf16x8 __attribute__((ext_vector_type(8)));
typedef float f32x4 __attribute__((ext_vector_type(4)));

// ---------------- workspace layout ----------------
#define OFF_CNT  0                         // 8 ints
#define OFF_LIST 1024                      // NE*CAP ints  = 256 KB
#define OFF_WP   (OFF_LIST + NE*CAP*4)     // NPAIR floats = 32 KB
// fallback path
#define OFF_H1   (OFF_WP + NPAIR*4)
// fast path
#define OFF_XB   ((size_t)1 << 20)                  // 8 MB  (NTOK*DIM bf16)
#define OFF_W2B  ((size_t)10 << 20)                 // 46.14 MB (NE*DIM*HID bf16)
#define OFF_H2   ((size_t)57 << 20)                 // 46.14 MB (NPAIR*HID bf16)
#define OFF_OB   ((size_t)104 << 20)                // 16.78 MB (NPAIR*DIM bf16)
#define WS_NEED  (OFF_OB + (size_t)NPAIR * DIM * 2) // ~121 MB

#define GLB(p) ((const __attribute__((address_space(1))) void*)(p))
#define LDS(p) ((__attribute__((address_space(3))) void*)(p))

__device__ __forceinline__ bf16x8 pack8(float4 a, float4 b) {
  bf16x8 v;
  v[0] = (__bf16)a.x; v[1] = (__bf16)a.y; v[2] = (__bf16)a.z; v[3] = (__bf16)a.w;
  v[4] = (__bf16)b.x; v[5] = (__bf16)b.y; v[6] = (__bf16)b.z; v[7] = (__bf16)b.w;
  return v;
}

// ---------------- gating (+ x -> bf16 in fast path) -------------------------
__global__ __launch_bounds__(64) void gate_kernel(
    const float* __restrict__ x, const float* __restrict__ Wg,
    int* __restrict__ counts, int* __restrict__ list, float* __restrict__ wpair,
    __bf16* __restrict__ xb) {
  int t = blockIdx.x;
  int lane = threadIdx.x;
  const float* xp = x + (size_t)t * DIM;
  float xr[16];
#pragma unroll
  for (int i = 0; i < 16; ++i) xr[i] = xp[lane + 64 * i];
  if (xb) {
    __bf16* xo = xb + (size_t)t * DIM;
#pragma unroll
    for (int i = 0; i < 16; ++i) xo[lane + 64 * i] = (__bf16)xr[i];
  }
  float s[NE];
#pragma unroll
  for (int e = 0; e < NE; ++e) {
    const float* wp = Wg + e * DIM;
    float acc = 0.f;
#pragma unroll
    for (int i = 0; i < 16; ++i) acc += xr[i] * wp[lane + 64 * i];
#pragma unroll
    for (int off = 32; off >= 1; off >>= 1) acc += __shfl_xor(acc, off, 64);
    s[e] = acc;
  }
  if (lane == 0) {
    int i0 = 0; float b0 = s[0];
#pragma unroll
    for (int e = 1; e < NE; ++e) if (s[e] > b0) { b0 = s[e]; i0 = e; }
    int i1 = -1; float b1 = -1e30f;
#pragma unroll
    for (int e = 0; e < NE; ++e) if (e != i0 && s[e] > b1) { b1 = s[e]; i1 = e; }
    float e1 = __expf(b1 - b0);
    float w0 = 1.f / (1.f + e1);
    float w1 = e1 * w0;
    int s0 = atomicAdd(&counts[i0], 1);
    list[i0 * CAP + s0] = 2 * t;
    wpair[2 * t] = w0;
    int s1 = atomicAdd(&counts[i1], 1);
    list[i1 * CAP + s1] = 2 * t + 1;
    wpair[2 * t + 1] = w1;
  }
}

// ---------------- fp32 -> bf16 streaming convert (W2 only) ------------------
__global__ __launch_bounds__(256) void cvt_kernel(
    const float* __restrict__ src, __bf16* __restrict__ dst) {
  size_t i = (((size_t)blockIdx.x * 256) + threadIdx.x) * 8;
  float4 f0 = *(const float4*)(src + i);
  float4 f1 = *(const float4*)(src + i + 4);
  *(bf16x8*)(dst + i) = pack8(f0, f1);
}

// =============== up7: resident-B panel kernel ===============================
// One block per (expert, 16 h-cols). Panel of W1/W3 (16 rows x 1024 K each)
// converted fp32->bf16 into LDS ONCE (weights read exactly once chip-wide).
// Then loop over all M-tiles (BM=128, 4 waves x 32 rows) with A fragments in
// REGISTERS (direct gathered loads from xb, 2-step lookahead via full unroll).
// No barriers in the main loop. B LDS swizzle: chunk c16 ^= (row&7).
__global__ __launch_bounds__(256) void up7_kernel(
    const __bf16* __restrict__ xb, const float* __restrict__ W1,
    const float* __restrict__ W3, const int* __restrict__ counts,
    const int* __restrict__ list, const float* __restrict__ wpair,
    __bf16* __restrict__ Hbuf) {
  int g = blockIdx.x;
  int e = g / (HID / 16);
  int h0 = (g % (HID / 16)) * 16;
  int cnt = counts[e];

  __shared__ __bf16 B1s[16 * 1024];   // 32 KB
  __shared__ __bf16 B3s[16 * 1024];   // 32 KB

  int tid = threadIdx.x;
  int lane = tid & 63;
  int w = tid >> 6;
  int cl = lane & 15, hi = lane >> 4;

  // ---- B panel init: row = tid>>4 (0..15), chunks c16 = (tid&15) + 16*i ----
  {
    int row = tid >> 4;
    const float* w1p = W1 + ((size_t)e * HID + h0 + row) * DIM;
    const float* w3p = W3 + ((size_t)e * HID + h0 + row) * DIM;
#pragma unroll
    for (int i = 0; i < 8; ++i) {
      int c16 = (tid & 15) + 16 * i;
      int dst = row * 2048 + ((c16 ^ (row & 7)) * 16);
      float4 a0 = *(const float4*)(w1p + c16 * 8);
      float4 a1 = *(const float4*)(w1p + c16 * 8 + 4);
      *(bf16x8*)((char*)B1s + dst) = pack8(a0, a1);
      float4 b0 = *(const float4*)(w3p + c16 * 8);
      float4 b1v = *(const float4*)(w3p + c16 * 8 + 4);
      *(bf16x8*)((char*)B3s + dst) = pack8(b0, b1v);
    }
  }
  __syncthreads();

  int nmt = (cnt + 127) >> 7;
  const int* lste = list + e * CAP;

  for (int mt = 0; mt < nmt; ++mt) {
    int m0 = mt * 128;
    // per-lane A row indices for this m-tile (frag row = lane&15)
    size_t apos[2];
#pragma unroll
    for (int mi = 0; mi < 2; ++mi) {
      int r = m0 + w * 32 + mi * 16 + cl;
      if (r > cnt - 1) r = cnt - 1;
      int p = lste[r];
      apos[mi] = (size_t)(p >> 1) * DIM + hi * 8;
    }

    f32x4 acc1[2] = {};
    f32x4 acc3[2] = {};

    bf16x8 af[2][2][2];  // [parity][mi][ks]
#pragma unroll
    for (int kt = 0; kt < 2; ++kt)
#pragma unroll
      for (int mi = 0; mi < 2; ++mi)
#pragma unroll
        for (int ks = 0; ks < 2; ++ks)
          af[kt][mi][ks] = *(const bf16x8*)(xb + apos[mi] + kt * 64 + ks * 32);

#pragma unroll
    for (int kt = 0; kt < 16; ++kt) {
      int par = kt & 1;
      bf16x8 b1f[2], b3f[2];
#pragma unroll
      for (int ks = 0; ks < 2; ++ks) {
        int c16 = kt * 8 + ks * 4 + hi;
        int off = cl * 2048 + ((c16 ^ (cl & 7)) * 16);
        b1f[ks] = *(const bf16x8*)((const char*)B1s + off);
        b3f[ks] = *(const bf16x8*)((const char*)B3s + off);
      }
#pragma unroll
      for (int ks = 0; ks < 2; ++ks)
#pragma unroll
        for (int mi = 0; mi < 2; ++mi) {
          acc1[mi] = __builtin_amdgcn_mfma_f32_16x16x32_bf16(af[par][mi][ks], b1f[ks], acc1[mi], 0, 0, 0);
          acc3[mi] = __builtin_amdgcn_mfma_f32_16x16x32_bf16(af[par][mi][ks], b3f[ks], acc3[mi], 0, 0, 0);
        }
      if (kt + 2 < 16) {
#pragma unroll
        for (int mi = 0; mi < 2; ++mi)
#pragma unroll
          for (int ks = 0; ks < 2; ++ks)
            af[par][mi][ks] = *(const bf16x8*)(xb + apos[mi] + (kt + 2) * 64 + ks * 32);
      }
    }

    // epilogue: H[p][h0+cl] = wpair * silu(h1) * h3
#pragma unroll
    for (int mi = 0; mi < 2; ++mi) {
#pragma unroll
      for (int rr = 0; rr < 4; ++rr) {
        int m = m0 + w * 32 + mi * 16 + hi * 4 + rr;
        if (m < cnt) {
          int p = lste[m];
          float wgt = wpair[p];
          float v1 = acc1[mi][rr], v3 = acc3[mi][rr];
          float gv = (v1 / (1.f + __expf(-v1))) * v3 * wgt;
          Hbuf[(size_t)p * HID + h0 + cl] = (__bf16)gv;
        }
      }
    }
  }
}

// =============== down6: counted-vmcnt 3-deep pipeline =======================
// 128(M) x 64(N) x K=2816 tile, 4 waves (2Mx2N). A (Hbuf rows, gathered) and
// B (W2b) staged via global_load_lds into 3-deep LDS slots; per step: issue
// j+2 (6 loads), compute j, s_waitcnt vmcnt(6), raw s_barrier (T3/T4).
__global__ __launch_bounds__(256, 2) void down6_kernel(
    const __bf16* __restrict__ Hbuf, const __bf16* __restrict__ w2b,
    const int* __restrict__ counts, const int* __restrict__ list,
    __bf16* __restrict__ Obuf) {
  int g = blockIdx.x;
  int e = g >> 8;
  int rem = g & 255;
  int m0 = (rem & 15) * 128;       // M fastest: 16 blocks share each B panel
  int d0 = (rem >> 4) * 64;
  int cnt = counts[e];
  if (m0 >= cnt) return;

  __shared__ __bf16 As[3][128 * 64];  // 48 KB
  __shared__ __bf16 Bs[3][64 * 64];   // 24 KB

  int tid = threadIdx.x;
  int lane = tid & 63;
  int w = tid >> 6;
  int wr = w >> 1, wc = w & 1;
  int cl = lane & 15, hi = lane >> 4;

  const __bf16* asrc[4];
  const __bf16* bsrc[2];
  {
    int cc = tid & 7;
#pragma unroll
    for (int i = 0; i < 4; ++i) {
      int r = i * 32 + (tid >> 3);
      int csel = (cc ^ (r & 7)) * 8;
      int mrow = m0 + r; if (mrow > cnt - 1) mrow = cnt - 1;
      int p = list[e * CAP + mrow];
      asrc[i] = Hbuf + (size_t)p * HID + csel;
    }
#pragma unroll
    for (int i = 0; i < 2; ++i) {
      int r = i * 32 + (tid >> 3);
      int csel = (cc ^ (r & 7)) * 8;
      bsrc[i] = w2b + ((size_t)e * DIM + d0 + r) * HID + csel;
    }
  }

  f32x4 acc[4][2] = {};

#define DN6_ISSUE(slot, j)                                                       \
  { int k0 = (j) * 64;                                                           \
    _Pragma("unroll") for (int i = 0; i < 4; ++i)                                \
      __builtin_amdgcn_global_load_lds(GLB(asrc[i] + k0),                        \
          LDS((char*)As + (slot) * 16384 + i * 4096 + tid * 16), 16, 0, 0);      \
    _Pragma("unroll") for (int i = 0; i < 2; ++i)                                \
      __builtin_amdgcn_global_load_lds(GLB(bsrc[i] + k0),                        \
          LDS((char*)Bs + (slot) * 8192 + i * 4096 + tid * 16), 16, 0, 0); }

#define DN6_COMPUTE(slot)                                                        \
  { const char* Ab = (const char*)As + (slot) * 16384;                           \
    const char* Bb = (const char*)Bs + (slot) * 8192;                            \
    _Pragma("unroll") for (int ks = 0; ks < 2; ++ks) {                           \
      int c = hi + ks * 4;                                                       \
      bf16x8 a[4], b[2];                                                         \
      _Pragma("unroll") for (int mi = 0; mi < 4; ++mi) {                         \
        int r = wr * 64 + mi * 16 + cl;                                          \
        a[mi] = *(const bf16x8*)(Ab + r * 128 + ((c ^ (r & 7)) * 16));           \
      }                                                                          \
      _Pragma("unroll") for (int ni = 0; ni < 2; ++ni) {                         \
        int r = wc * 32 + ni * 16 + cl;                                          \
        b[ni] = *(const bf16x8*)(Bb + r * 128 + ((c ^ (r & 7)) * 16));           \
      }                                                                          \
      _Pragma("unroll") for (int mi = 0; mi < 4; ++mi)                           \
        _Pragma("unroll") for (int ni = 0; ni < 2; ++ni)                         \
          acc[mi][ni] = __builtin_amdgcn_mfma_f32_16x16x32_bf16(a[mi], b[ni], acc[mi][ni], 0, 0, 0); \
  } }

  DN6_ISSUE(0, 0)
  DN6_ISSUE(1, 1)
  asm volatile("s_waitcnt vmcnt(6)" ::: "memory");
  asm volatile("s_barrier" ::: "memory");

  int sc = 0;                      // compute slot = j % 3
#pragma unroll 1
  for (int j = 0; j < HID / 64; ++j) {
    int si = sc + 2; if (si >= 3) si -= 3;   // issue slot = (j+2) % 3
    if (j < HID / 64 - 2) { DN6_ISSUE(si, j + 2) }
    __builtin_amdgcn_sched_barrier(0);
    DN6_COMPUTE(sc)
    if (j < HID / 64 - 2) {
      asm volatile("s_waitcnt vmcnt(6)" ::: "memory");
    } else {
      asm volatile("s_waitcnt vmcnt(0)" ::: "memory");
    }
    asm volatile("s_barrier" ::: "memory");
    ++sc; if (sc == 3) sc = 0;
  }

#pragma unroll
  for (int mi = 0; mi < 4; ++mi) {
#pragma unroll
    for (int rr = 0; rr < 4; ++rr) {
      int m = m0 + wr * 64 + mi * 16 + hi * 4 + rr;
      if (m < cnt) {
        int p = list[e * CAP + m];
        __bf16* op = Obuf + (size_t)p * DIM + d0 + wc * 32 + cl;
#pragma unroll
        for (int ni = 0; ni < 2; ++ni)
          op[ni * 16] = (__bf16)acc[mi][ni][rr];
      }
    }
  }
}

// ---------------- combine: out[t] = Obuf[2t] + Obuf[2t+1] -------------------
__global__ __launch_bounds__(256) void combine_kernel(
    const __bf16* __restrict__ Obuf, float* __restrict__ out) {
  size_t j = (((size_t)blockIdx.x * 256) + threadIdx.x) * 8;
  size_t t = j >> 10;
  bf16x8 a = *(const bf16x8*)(Obuf + j + t * DIM);
  bf16x8 b = *(const bf16x8*)(Obuf + j + t * DIM + DIM);
  float4 o0, o1;
  o0.x = (float)a[0] + (float)b[0]; o0.y = (float)a[1] + (float)b[1];
  o0.z = (float)a[2] + (float)b[2]; o0.w = (float)a[3] + (float)b[3];
  o1.x = (float)a[4] + (float)b[4]; o1.y = (float)a[5] + (float)b[5];
  o1.z = (float)a[6] + (float)b[6]; o1.w = (float)a[7] + (float)b[7];
  *(float4*)(out + j) = o0;
  *(float4*)(out + j + 4) = o1;
}

// =============== fallback path (round-1 kernels) ============================
__device__ __forceinline__ void cvt_store16(__bf16* dst, const float* src) {
#pragma unroll
  for (int j = 0; j < 2; ++j) {
    float4 f0 = *(const float4*)(src + j * 8);
    float4 f1 = *(const float4*)(src + j * 8 + 4);
    *(bf16x8*)(dst + j * 8) = pack8(f0, f1);
  }
}

__global__ __launch_bounds__(256) void up_kernel(
    const float* __restrict__ x, const float* __restrict__ W1,
    const float* __restrict__ W3, const int* __restrict__ counts,
    const int* __restrict__ list, __bf16* __restrict__ Hbuf) {
  int e = blockIdx.z;
  int cnt = counts[e];
  int m0 = blockIdx.y * 64;
  if (m0 >= cnt) return;
  int h0 = blockIdx.x * 64;

  __shared__ __bf16 As[64][72];
  __shared__ __bf16 B1s[64][72];
  __shared__ __bf16 B3s[64][72];

  int tid = threadIdx.x;
  int r = tid >> 2;
  int cs = (tid & 3) * 16;

  const float* asrc = nullptr;
  int mrow = m0 + r;
  if (mrow < cnt) {
    int p = list[e * CAP + mrow];
    asrc = x + (size_t)(p >> 1) * DIM;
  }
  const float* b1src = W1 + ((size_t)e * HID + (h0 + r)) * DIM;
  const float* b3src = W3 + ((size_t)e * HID + (h0 + r)) * DIM;

  int lane = tid & 63;
  int w = tid >> 6;
  int wr = w >> 1, wc = w & 1;
  int cl = lane & 15, hi = lane >> 4;

  f32x4 acc1[2][2] = {};
  f32x4 acc3[2][2] = {};

  for (int k0 = 0; k0 < DIM; k0 += 64) {
    if (asrc) {
      cvt_store16(&As[r][cs], asrc + k0 + cs);
    } else {
      bf16x8 z = {};
      *(bf16x8*)&As[r][cs] = z;
      *(bf16x8*)&As[r][cs + 8] = z;
    }
    cvt_store16(&B1s[r][cs], b1src + k0 + cs);
    cvt_store16(&B3s[r][cs], b3src + k0 + cs);
    __syncthreads();
#pragma unroll
    for (int ks = 0; ks < 64; ks += 32) {
      bf16x8 a[2], b1f[2], b3f[2];
#pragma unroll
      for (int mi = 0; mi < 2; ++mi)
        a[mi] = *(const bf16x8*)&As[wr * 32 + mi * 16 + cl][ks + hi * 8];
#pragma unroll
      for (int ni = 0; ni < 2; ++ni) {
        b1f[ni] = *(const bf16x8*)&B1s[wc * 32 + ni * 16 + cl][ks + hi * 8];
        b3f[ni] = *(const bf16x8*)&B3s[wc * 32 + ni * 16 + cl][ks + hi * 8];
      }
#pragma unroll
      for (int mi = 0; mi < 2; ++mi)
#pragma unroll
        for (int ni = 0; ni < 2; ++ni) {
          acc1[mi][ni] = __builtin_amdgcn_mfma_f32_16x16x32_bf16(a[mi], b1f[ni], acc1[mi][ni], 0, 0, 0);
          acc3[mi][ni] = __builtin_amdgcn_mfma_f32_16x16x32_bf16(a[mi], b3f[ni], acc3[mi][ni], 0, 0, 0);
        }
    }
    __syncthreads();
  }

#pragma unroll
  for (int mi = 0; mi < 2; ++mi) {
#pragma unroll
    for (int rr = 0; rr < 4; ++rr) {
      int m = m0 + wr * 32 + mi * 16 + hi * 4 + rr;
      if (m < cnt) {
        int p = list[e * CAP + m];
        __bf16* hp = Hbuf + (size_t)p * HID + h0 + wc * 32 + cl;
#pragma unroll
        for (int ni = 0; ni < 2; ++ni) {
          float v1 = acc1[mi][ni][rr], v3 = acc3[mi][ni][rr];
          float gg = (v1 / (1.f + __expf(-v1))) * v3;
          hp[ni * 16] = (__bf16)gg;
        }
      }
    }
  }
}

__global__ __launch_bounds__(256) void down_kernel(
    const __bf16* __restrict__ Hbuf, const float* __restrict__ W2,
    const int* __restrict__ counts, const int* __restrict__ list,
    const float* __restrict__ wpair, float* __restrict__ out) {
  int e = blockIdx.z;
  int cnt = counts[e];
  int m0 = blockIdx.y * 64;
  if (m0 >= cnt) return;
  int d0 = blockIdx.x * 64;

  __shared__ __bf16 As[64][72];
  __shared__ __bf16 Bs[64][72];

  int tid = threadIdx.x;
  int r = tid >> 2;
  int cs = (tid & 3) * 16;

  const __bf16* asrc = nullptr;
  int mrow = m0 + r;
  if (mrow < cnt) {
    int p = list[e * CAP + mrow];
    asrc = Hbuf + (size_t)p * HID;
  }
  const float* bsrc = W2 + ((size_t)e * DIM + (d0 + r)) * HID;

  int lane = tid & 63;
  int w = tid >> 6;
  int wr = w >> 1, wc = w & 1;
  int cl = lane & 15, hi = lane >> 4;

  f32x4 acc[2][2] = {};

  for (int k0 = 0; k0 < HID; k0 += 64) {
    if (asrc) {
      *(bf16x8*)&As[r][cs]     = *(const bf16x8*)(asrc + k0 + cs);
      *(bf16x8*)&As[r][cs + 8] = *(const bf16x8*)(asrc + k0 + cs + 8);
    } else {
      bf16x8 z = {};
      *(bf16x8*)&As[r][cs] = z;
      *(bf16x8*)&As[r][cs + 8] = z;
    }
    cvt_store16(&Bs[r][cs], bsrc + k0 + cs);
    __syncthreads();
#pragma unroll
    for (int ks = 0; ks < 64; ks += 32) {
      bf16x8 a[2], b[2];
#pragma unroll
      for (int mi = 0; mi < 2; ++mi)
        a[mi] = *(const bf16x8*)&As[wr * 32 + mi * 16 + cl][ks + hi * 8];
#pragma unroll
      for (int ni = 0; ni < 2; ++ni)
        b[ni] = *(const bf16x8*)&Bs[wc * 32 + ni * 16 + cl][ks + hi * 8];
#pragma unroll
      for (int mi = 0; mi < 2; ++mi)
#pragma unroll
        for (int ni = 0; ni < 2; ++ni)
          acc[mi][ni] = __builtin_amdgcn_mfma_f32_16x16x32_bf16(a[mi], b[ni], acc[mi][ni], 0, 0, 0);
    }
    __syncthreads();
  }

#pragma unroll
  for (int mi = 0; mi < 2; ++mi) {
#pragma unroll
    for (int rr = 0; rr < 4; ++rr) {
      int m = m0 + wr * 32 + mi * 16 + hi * 4 + rr;
      if (m < cnt) {
        int p = list[e * CAP + m];
        int t = p >> 1;
        float wgt = wpair[p];
        float* op = out + (size_t)t * DIM + d0 + wc * 32 + cl;
#pragma unroll
        for (int ni = 0; ni < 2; ++ni)
          atomicAdd(&op[ni * 16], wgt * acc[mi][ni][rr]);
      }
    }
  }
}

extern "C" void kernel_launch(void* const* d_in, const int* in_sizes, int n_in,
                              void* d_out, int out_size, void* d_ws, size_t ws_size,
                              hipStream_t stream) {
  const float* x  = (const float*)d_in[0];
  const float* Wg = (const float*)d_in[1];
  const float* W1 = (const float*)d_in[2];
  const float* W3 = (const float*)d_in[3];
  const float* W2 = (const float*)d_in[4];
  float* out = (float*)d_out;

  char* ws = (char*)d_ws;
  int* counts  = (int*)(ws + OFF_CNT);
  int* list    = (int*)(ws + OFF_LIST);
  float* wpair = (float*)(ws + OFF_WP);

  hipMemsetAsync(counts, 0, 64, stream);

  if (ws_size >= WS_NEED) {
    __bf16* xb   = (__bf16*)(ws + OFF_XB);
    __bf16* w2b  = (__bf16*)(ws + OFF_W2B);
    __bf16* Hbuf = (__bf16*)(ws + OFF_H2);
    __bf16* Obuf = (__bf16*)(ws + OFF_OB);

    gate_kernel<<<NTOK, 64, 0, stream>>>(x, Wg, counts, list, wpair, xb);

    cvt_kernel<<<NE * DIM * HID / 2048, 256, 0, stream>>>(W2, w2b);

    up7_kernel<<<NE * (HID / 16), 256, 0, stream>>>(xb, W1, W3, counts, list, wpair, Hbuf);

    down6_kernel<<<NE * 256, 256, 0, stream>>>(Hbuf, w2b, counts, list, Obuf);

    combine_kernel<<<NTOK * DIM / 2048, 256, 0, stream>>>(Obuf, out);
  } else {
    hipMemsetAsync(d_out, 0, (size_t)out_size * sizeof(float), stream);
    __bf16* Hbuf = (__bf16*)(ws + OFF_H1);
    gate_kernel<<<NTOK, 64, 0, stream>>>(x, Wg, counts, list, wpair, nullptr);
    up_kernel<<<dim3(HID / 64, CAP / 64, NE), 256, 0, stream>>>(x, W1, W3, counts, list, Hbuf);
    down_kernel<<<dim3(DIM / 64, CAP / 64, NE), 256, 0, stream>>>(Hbuf, W2, counts, list, wpair, out);
  }
}

// Round 7
// 629.423 us; speedup vs baseline: 1.8451x; 1.8451x over previous
//
#include <hip/hip_runtime.h>
#include <hip/hip_bf16.h>

#define DIM  1024
#define HID  2816
#define NE   8
#define NTOK 4096
#define NPAIR 8192
#define CAP  8192

typedef __bf16 bf16x8 __attribute__((ext_vector_type(8)));
typedef float f32x4 __attribute__((ext_vector_type(4)));

// ---------------- workspace layout ----------------
#define OFF_CNT  0                         // 8 ints
#define OFF_LIST 1024                      // NE*CAP ints  = 256 KB
#define OFF_WP   (OFF_LIST + NE*CAP*4)     // NPAIR floats = 32 KB
// fallback path
#define OFF_H1   (OFF_WP + NPAIR*4)
// fast path
#define OFF_XB   ((size_t)1 << 20)                  // 8 MB  (NTOK*DIM bf16)
#define OFF_H2   ((size_t)10 << 20)                 // 46.14 MB (NPAIR*HID bf16)
#define OFF_OB   ((size_t)57 << 20)                 // 16.78 MB (NPAIR*DIM bf16)
#define WS_NEED  (OFF_OB + (size_t)NPAIR * DIM * 2) // ~74 MB

#define GLB(p) ((const __attribute__((address_space(1))) void*)(p))
#define LDS(p) ((__attribute__((address_space(3))) void*)(p))

__device__ __forceinline__ bf16x8 pack8(float4 a, float4 b) {
  bf16x8 v;
  v[0] = (__bf16)a.x; v[1] = (__bf16)a.y; v[2] = (__bf16)a.z; v[3] = (__bf16)a.w;
  v[4] = (__bf16)b.x; v[5] = (__bf16)b.y; v[6] = (__bf16)b.z; v[7] = (__bf16)b.w;
  return v;
}

// ---------------- gating (+ x -> bf16 in fast path) -------------------------
__global__ __launch_bounds__(64) void gate_kernel(
    const float* __restrict__ x, const float* __restrict__ Wg,
    int* __restrict__ counts, int* __restrict__ list, float* __restrict__ wpair,
    __bf16* __restrict__ xb) {
  int t = blockIdx.x;
  int lane = threadIdx.x;
  const float* xp = x + (size_t)t * DIM;
  float xr[16];
#pragma unroll
  for (int i = 0; i < 16; ++i) xr[i] = xp[lane + 64 * i];
  if (xb) {
    __bf16* xo = xb + (size_t)t * DIM;
#pragma unroll
    for (int i = 0; i < 16; ++i) xo[lane + 64 * i] = (__bf16)xr[i];
  }
  float s[NE];
#pragma unroll
  for (int e = 0; e < NE; ++e) {
    const float* wp = Wg + e * DIM;
    float acc = 0.f;
#pragma unroll
    for (int i = 0; i < 16; ++i) acc += xr[i] * wp[lane + 64 * i];
#pragma unroll
    for (int off = 32; off >= 1; off >>= 1) acc += __shfl_xor(acc, off, 64);
    s[e] = acc;
  }
  if (lane == 0) {
    int i0 = 0; float b0 = s[0];
#pragma unroll
    for (int e = 1; e < NE; ++e) if (s[e] > b0) { b0 = s[e]; i0 = e; }
    int i1 = -1; float b1 = -1e30f;
#pragma unroll
    for (int e = 0; e < NE; ++e) if (e != i0 && s[e] > b1) { b1 = s[e]; i1 = e; }
    float e1 = __expf(b1 - b0);
    float w0 = 1.f / (1.f + e1);
    float w1 = e1 * w0;
    int s0 = atomicAdd(&counts[i0], 1);
    list[i0 * CAP + s0] = 2 * t;
    wpair[2 * t] = w0;
    int s1 = atomicAdd(&counts[i1], 1);
    list[i1 * CAP + s1] = 2 * t + 1;
    wpair[2 * t + 1] = w1;
  }
}

// =============== fast path ==================================================
// 128x128x64 tiles, 4 waves (2Mx2N). N-tile-fastest grid (A-panel L2-resident,
// B streams; r2-proven order). A (bf16): global_load_lds, DOUBLE-buffered,
// issued a full compute-phase early. B (fp32 weights, read directly — no cvt
// kernels): reg-staged float4 loads issued a phase early (T14), packed to bf16
// and ds_written swizzled after the barrier. Raw s_barrier + explicit
// vmcnt/lgkmcnt so prefetch survives the barrier (no vmcnt(0)-drain from
// __syncthreads). LDS chunk swizzle c ^= (row&7) on both sides (rule #21).

// ---------------- up6: H[p][:] = wpair * silu(x.W1^T) * (x.W3^T) ------------
__global__ __launch_bounds__(256, 2) void up6_kernel(
    const __bf16* __restrict__ xb, const float* __restrict__ W1,
    const float* __restrict__ W3, const int* __restrict__ counts,
    const int* __restrict__ list, const float* __restrict__ wpair,
    __bf16* __restrict__ Hbuf) {
  int e = blockIdx.z;
  int cnt = counts[e];
  int m0 = blockIdx.y * 128;
  if (m0 >= cnt) return;
  int h0 = blockIdx.x * 128;

  __shared__ __bf16 As[2][128 * 64];   // 32 KB (dbuf)
  __shared__ __bf16 B1s[128 * 64];     // 16 KB
  __shared__ __bf16 B3s[128 * 64];     // 16 KB

  int tid = threadIdx.x;
  int lane = tid & 63;
  int w = tid >> 6;
  int wr = w >> 1, wc = w & 1;
  int cl = lane & 15, hi = lane >> 4;

  const __bf16* asrc[4];
  {
    int cc = tid & 7;
#pragma unroll
    for (int i = 0; i < 4; ++i) {
      int r = i * 32 + (tid >> 3);
      int csel = (cc ^ (r & 7)) * 8;
      int mrow = m0 + r; if (mrow > cnt - 1) mrow = cnt - 1;
      int p = list[e * CAP + mrow];
      asrc[i] = xb + (size_t)(p >> 1) * DIM + csel;
    }
  }

  // B fp32 sources: row rb (0..127), half hb covers 32 K-cols
  int rb = tid >> 1, hb = tid & 1;
  const float* b1p = W1 + ((size_t)e * HID + h0 + rb) * DIM + hb * 32;
  const float* b3p = W3 + ((size_t)e * HID + h0 + rb) * DIM + hb * 32;
  char* d1 = (char*)B1s + rb * 128;
  char* d3 = (char*)B3s + rb * 128;
  int dc[4];
#pragma unroll
  for (int j = 0; j < 4; ++j) dc[j] = ((hb * 4 + j) ^ (rb & 7)) * 16;

  f32x4 acc1[4][4] = {};
  f32x4 acc3[4][4] = {};
  float4 r1[8], r3[8];

#define U6_LOADB(k0)                                                           \
  { _Pragma("unroll") for (int j = 0; j < 8; ++j) {                            \
      r1[j] = *(const float4*)(b1p + (k0) + j * 4);                            \
      r3[j] = *(const float4*)(b3p + (k0) + j * 4); } }
#define U6_WRITEB()                                                            \
  { _Pragma("unroll") for (int j = 0; j < 4; ++j) {                            \
      *(bf16x8*)(d1 + dc[j]) = pack8(r1[2 * j], r1[2 * j + 1]);                \
      *(bf16x8*)(d3 + dc[j]) = pack8(r3[2 * j], r3[2 * j + 1]); } }
#define U6_ISSUEA(buf, k0)                                                     \
  { _Pragma("unroll") for (int i = 0; i < 4; ++i)                              \
      __builtin_amdgcn_global_load_lds(GLB(asrc[i] + (k0)),                    \
          LDS((char*)As[buf] + i * 4096 + tid * 16), 16, 0, 0); }
#define U6_COMPUTE(buf)                                                        \
  { _Pragma("unroll") for (int ks = 0; ks < 2; ++ks) {                         \
      int c = hi + ks * 4;                                                     \
      bf16x8 a[4], f1[4], f3[4];                                               \
      _Pragma("unroll") for (int mi = 0; mi < 4; ++mi) {                       \
        int r = wr * 64 + mi * 16 + cl;                                        \
        a[mi] = *(const bf16x8*)((const char*)As[buf] + r * 128 + ((c ^ (r & 7)) * 16)); \
      }                                                                        \
      _Pragma("unroll") for (int ni = 0; ni < 4; ++ni) {                       \
        int r = wc * 64 + ni * 16 + cl;                                        \
        int o = r * 128 + ((c ^ (r & 7)) * 16);                                \
        f1[ni] = *(const bf16x8*)((const char*)B1s + o);                       \
        f3[ni] = *(const bf16x8*)((const char*)B3s + o);                       \
      }                                                                        \
      _Pragma("unroll") for (int mi = 0; mi < 4; ++mi)                         \
        _Pragma("unroll") for (int ni = 0; ni < 4; ++ni) {                     \
          acc1[mi][ni] = __builtin_amdgcn_mfma_f32_16x16x32_bf16(a[mi], f1[ni], acc1[mi][ni], 0, 0, 0); \
          acc3[mi][ni] = __builtin_amdgcn_mfma_f32_16x16x32_bf16(a[mi], f3[ni], acc3[mi][ni], 0, 0, 0); \
        }                                                                      \
  } }

  U6_LOADB(0)
  U6_ISSUEA(0, 0)

#pragma unroll 1
  for (int kt = 0; kt < DIM / 64; ++kt) {
    int buf = kt & 1;
    asm volatile("s_waitcnt vmcnt(0)" ::: "memory");   // A_kt in LDS, B_kt regs
    asm volatile("s_barrier" ::: "memory");            // prev compute done
    U6_WRITEB()
    if (kt + 1 < DIM / 64) {
      U6_ISSUEA(buf ^ 1, (kt + 1) * 64)                // in flight over compute
      U6_LOADB((kt + 1) * 64)
    }
    asm volatile("s_waitcnt lgkmcnt(0)" ::: "memory"); // ds_write visible
    asm volatile("s_barrier" ::: "memory");
    U6_COMPUTE(buf)
  }

#pragma unroll
  for (int mi = 0; mi < 4; ++mi) {
#pragma unroll
    for (int rr = 0; rr < 4; ++rr) {
      int m = m0 + wr * 64 + mi * 16 + hi * 4 + rr;
      if (m < cnt) {
        int p = list[e * CAP + m];
        float wgt = wpair[p];
        __bf16* hp = Hbuf + (size_t)p * HID + h0 + wc * 64 + cl;
#pragma unroll
        for (int ni = 0; ni < 4; ++ni) {
          float v1 = acc1[mi][ni][rr], v3 = acc3[mi][ni][rr];
          float gv = (v1 / (1.f + __expf(-v1))) * v3 * wgt;
          hp[ni * 16] = (__bf16)gv;
        }
      }
    }
  }
}

// ---------------- down7: Obuf[p][:] = H[p] . W2^T (fp32 W2 direct) ----------
__global__ __launch_bounds__(256, 3) void down7_kernel(
    const __bf16* __restrict__ Hbuf, const float* __restrict__ W2,
    const int* __restrict__ counts, const int* __restrict__ list,
    __bf16* __restrict__ Obuf) {
  int e = blockIdx.z;
  int cnt = counts[e];
  int m0 = blockIdx.y * 128;
  if (m0 >= cnt) return;
  int d0 = blockIdx.x * 128;

  __shared__ __bf16 As[2][128 * 64];   // 32 KB
  __shared__ __bf16 B2s[128 * 64];     // 16 KB

  int tid = threadIdx.x;
  int lane = tid & 63;
  int w = tid >> 6;
  int wr = w >> 1, wc = w & 1;
  int cl = lane & 15, hi = lane >> 4;

  const __bf16* asrc[4];
  {
    int cc = tid & 7;
#pragma unroll
    for (int i = 0; i < 4; ++i) {
      int r = i * 32 + (tid >> 3);
      int csel = (cc ^ (r & 7)) * 8;
      int mrow = m0 + r; if (mrow > cnt - 1) mrow = cnt - 1;
      int p = list[e * CAP + mrow];
      asrc[i] = Hbuf + (size_t)p * HID + csel;
    }
  }

  int rb = tid >> 1, hb = tid & 1;
  const float* b2p = W2 + ((size_t)e * DIM + d0 + rb) * HID + hb * 32;
  char* d2 = (char*)B2s + rb * 128;
  int dc[4];
#pragma unroll
  for (int j = 0; j < 4; ++j) dc[j] = ((hb * 4 + j) ^ (rb & 7)) * 16;

  f32x4 acc[4][4] = {};
  float4 r2[8];

#define D7_LOADB(k0)                                                           \
  { _Pragma("unroll") for (int j = 0; j < 8; ++j)                              \
      r2[j] = *(const float4*)(b2p + (k0) + j * 4); }
#define D7_WRITEB()                                                            \
  { _Pragma("unroll") for (int j = 0; j < 4; ++j)                              \
      *(bf16x8*)(d2 + dc[j]) = pack8(r2[2 * j], r2[2 * j + 1]); }
#define D7_ISSUEA(buf, k0)                                                     \
  { _Pragma("unroll") for (int i = 0; i < 4; ++i)                              \
      __builtin_amdgcn_global_load_lds(GLB(asrc[i] + (k0)),                    \
          LDS((char*)As[buf] + i * 4096 + tid * 16), 16, 0, 0); }
#define D7_COMPUTE(buf)                                                        \
  { _Pragma("unroll") for (int ks = 0; ks < 2; ++ks) {                         \
      int c = hi + ks * 4;                                                     \
      bf16x8 a[4], b[4];                                                       \
      _Pragma("unroll") for (int mi = 0; mi < 4; ++mi) {                       \
        int r = wr * 64 + mi * 16 + cl;                                        \
        a[mi] = *(const bf16x8*)((const char*)As[buf] + r * 128 + ((c ^ (r & 7)) * 16)); \
      }                                                                        \
      _Pragma("unroll") for (int ni = 0; ni < 4; ++ni) {                       \
        int r = wc * 64 + ni * 16 + cl;                                        \
        b[ni] = *(const bf16x8*)((const char*)B2s + r * 128 + ((c ^ (r & 7)) * 16)); \
      }                                                                        \
      _Pragma("unroll") for (int mi = 0; mi < 4; ++mi)                         \
        _Pragma("unroll") for (int ni = 0; ni < 4; ++ni)                       \
          acc[mi][ni] = __builtin_amdgcn_mfma_f32_16x16x32_bf16(a[mi], b[ni], acc[mi][ni], 0, 0, 0); \
  } }

  D7_LOADB(0)
  D7_ISSUEA(0, 0)

#pragma unroll 1
  for (int kt = 0; kt < HID / 64; ++kt) {
    int buf = kt & 1;
    asm volatile("s_waitcnt vmcnt(0)" ::: "memory");
    asm volatile("s_barrier" ::: "memory");
    D7_WRITEB()
    if (kt + 1 < HID / 64) {
      D7_ISSUEA(buf ^ 1, (kt + 1) * 64)
      D7_LOADB((kt + 1) * 64)
    }
    asm volatile("s_waitcnt lgkmcnt(0)" ::: "memory");
    asm volatile("s_barrier" ::: "memory");
    D7_COMPUTE(buf)
  }

#pragma unroll
  for (int mi = 0; mi < 4; ++mi) {
#pragma unroll
    for (int rr = 0; rr < 4; ++rr) {
      int m = m0 + wr * 64 + mi * 16 + hi * 4 + rr;
      if (m < cnt) {
        int p = list[e * CAP + m];
        __bf16* op = Obuf + (size_t)p * DIM + d0 + wc * 64 + cl;
#pragma unroll
        for (int ni = 0; ni < 4; ++ni)
          op[ni * 16] = (__bf16)acc[mi][ni][rr];
      }
    }
  }
}

// ---------------- combine: out[t] = Obuf[2t] + Obuf[2t+1] -------------------
__global__ __launch_bounds__(256) void combine_kernel(
    const __bf16* __restrict__ Obuf, float* __restrict__ out) {
  size_t j = (((size_t)blockIdx.x * 256) + threadIdx.x) * 8;
  size_t t = j >> 10;
  bf16x8 a = *(const bf16x8*)(Obuf + j + t * DIM);
  bf16x8 b = *(const bf16x8*)(Obuf + j + t * DIM + DIM);
  float4 o0, o1;
  o0.x = (float)a[0] + (float)b[0]; o0.y = (float)a[1] + (float)b[1];
  o0.z = (float)a[2] + (float)b[2]; o0.w = (float)a[3] + (float)b[3];
  o1.x = (float)a[4] + (float)b[4]; o1.y = (float)a[5] + (float)b[5];
  o1.z = (float)a[6] + (float)b[6]; o1.w = (float)a[7] + (float)b[7];
  *(float4*)(out + j) = o0;
  *(float4*)(out + j + 4) = o1;
}

// =============== fallback path (round-1 kernels) ============================
__device__ __forceinline__ void cvt_store16(__bf16* dst, const float* src) {
#pragma unroll
  for (int j = 0; j < 2; ++j) {
    float4 f0 = *(const float4*)(src + j * 8);
    float4 f1 = *(const float4*)(src + j * 8 + 4);
    *(bf16x8*)(dst + j * 8) = pack8(f0, f1);
  }
}

__global__ __launch_bounds__(256) void up_kernel(
    const float* __restrict__ x, const float* __restrict__ W1,
    const float* __restrict__ W3, const int* __restrict__ counts,
    const int* __restrict__ list, __bf16* __restrict__ Hbuf) {
  int e = blockIdx.z;
  int cnt = counts[e];
  int m0 = blockIdx.y * 64;
  if (m0 >= cnt) return;
  int h0 = blockIdx.x * 64;

  __shared__ __bf16 As[64][72];
  __shared__ __bf16 B1s[64][72];
  __shared__ __bf16 B3s[64][72];

  int tid = threadIdx.x;
  int r = tid >> 2;
  int cs = (tid & 3) * 16;

  const float* asrc = nullptr;
  int mrow = m0 + r;
  if (mrow < cnt) {
    int p = list[e * CAP + mrow];
    asrc = x + (size_t)(p >> 1) * DIM;
  }
  const float* b1src = W1 + ((size_t)e * HID + (h0 + r)) * DIM;
  const float* b3src = W3 + ((size_t)e * HID + (h0 + r)) * DIM;

  int lane = tid & 63;
  int w = tid >> 6;
  int wr = w >> 1, wc = w & 1;
  int cl = lane & 15, hi = lane >> 4;

  f32x4 acc1[2][2] = {};
  f32x4 acc3[2][2] = {};

  for (int k0 = 0; k0 < DIM; k0 += 64) {
    if (asrc) {
      cvt_store16(&As[r][cs], asrc + k0 + cs);
    } else {
      bf16x8 z = {};
      *(bf16x8*)&As[r][cs] = z;
      *(bf16x8*)&As[r][cs + 8] = z;
    }
    cvt_store16(&B1s[r][cs], b1src + k0 + cs);
    cvt_store16(&B3s[r][cs], b3src + k0 + cs);
    __syncthreads();
#pragma unroll
    for (int ks = 0; ks < 64; ks += 32) {
      bf16x8 a[2], b1f[2], b3f[2];
#pragma unroll
      for (int mi = 0; mi < 2; ++mi)
        a[mi] = *(const bf16x8*)&As[wr * 32 + mi * 16 + cl][ks + hi * 8];
#pragma unroll
      for (int ni = 0; ni < 2; ++ni) {
        b1f[ni] = *(const bf16x8*)&B1s[wc * 32 + ni * 16 + cl][ks + hi * 8];
        b3f[ni] = *(const bf16x8*)&B3s[wc * 32 + ni * 16 + cl][ks + hi * 8];
      }
#pragma unroll
      for (int mi = 0; mi < 2; ++mi)
#pragma unroll
        for (int ni = 0; ni < 2; ++ni) {
          acc1[mi][ni] = __builtin_amdgcn_mfma_f32_16x16x32_bf16(a[mi], b1f[ni], acc1[mi][ni], 0, 0, 0);
          acc3[mi][ni] = __builtin_amdgcn_mfma_f32_16x16x32_bf16(a[mi], b3f[ni], acc3[mi][ni], 0, 0, 0);
        }
    }
    __syncthreads();
  }

#pragma unroll
  for (int mi = 0; mi < 2; ++mi) {
#pragma unroll
    for (int rr = 0; rr < 4; ++rr) {
      int m = m0 + wr * 32 + mi * 16 + hi * 4 + rr;
      if (m < cnt) {
        int p = list[e * CAP + m];
        __bf16* hp = Hbuf + (size_t)p * HID + h0 + wc * 32 + cl;
#pragma unroll
        for (int ni = 0; ni < 2; ++ni) {
          float v1 = acc1[mi][ni][rr], v3 = acc3[mi][ni][rr];
          float gg = (v1 / (1.f + __expf(-v1))) * v3;
          hp[ni * 16] = (__bf16)gg;
        }
      }
    }
  }
}

__global__ __launch_bounds__(256) void down_kernel(
    const __bf16* __restrict__ Hbuf, const float* __restrict__ W2,
    const int* __restrict__ counts, const int* __restrict__ list,
    const float* __restrict__ wpair, float* __restrict__ out) {
  int e = blockIdx.z;
  int cnt = counts[e];
  int m0 = blockIdx.y * 64;
  if (m0 >= cnt) return;
  int d0 = blockIdx.x * 64;

  __shared__ __bf16 As[64][72];
  __shared__ __bf16 Bs[64][72];

  int tid = threadIdx.x;
  int r = tid >> 2;
  int cs = (tid & 3) * 16;

  const __bf16* asrc = nullptr;
  int mrow = m0 + r;
  if (mrow < cnt) {
    int p = list[e * CAP + mrow];
    asrc = Hbuf + (size_t)p * HID;
  }
  const float* bsrc = W2 + ((size_t)e * DIM + (d0 + r)) * HID;

  int lane = tid & 63;
  int w = tid >> 6;
  int wr = w >> 1, wc = w & 1;
  int cl = lane & 15, hi = lane >> 4;

  f32x4 acc[2][2] = {};

  for (int k0 = 0; k0 < HID; k0 += 64) {
    if (asrc) {
      *(bf16x8*)&As[r][cs]     = *(const bf16x8*)(asrc + k0 + cs);
      *(bf16x8*)&As[r][cs + 8] = *(const bf16x8*)(asrc + k0 + cs + 8);
    } else {
      bf16x8 z = {};
      *(bf16x8*)&As[r][cs] = z;
      *(bf16x8*)&As[r][cs + 8] = z;
    }
    cvt_store16(&Bs[r][cs], bsrc + k0 + cs);
    __syncthreads();
#pragma unroll
    for (int ks = 0; ks < 64; ks += 32) {
      bf16x8 a[2], b[2];
#pragma unroll
      for (int mi = 0; mi < 2; ++mi)
        a[mi] = *(const bf16x8*)&As[wr * 32 + mi * 16 + cl][ks + hi * 8];
#pragma unroll
      for (int ni = 0; ni < 2; ++ni)
        b[ni] = *(const bf16x8*)&Bs[wc * 32 + ni * 16 + cl][ks + hi * 8];
#pragma unroll
      for (int mi = 0; mi < 2; ++mi)
#pragma unroll
        for (int ni = 0; ni < 2; ++ni)
          acc[mi][ni] = __builtin_amdgcn_mfma_f32_16x16x32_bf16(a[mi], b[ni], acc[mi][ni], 0, 0, 0);
    }
    __syncthreads();
  }

#pragma unroll
  for (int mi = 0; mi < 2; ++mi) {
#pragma unroll
    for (int rr = 0; rr < 4; ++rr) {
      int m = m0 + wr * 32 + mi * 16 + hi * 4 + rr;
      if (m < cnt) {
        int p = list[e * CAP + m];
        int t = p >> 1;
        float wgt = wpair[p];
        float* op = out + (size_t)t * DIM + d0 + wc * 32 + cl;
#pragma unroll
        for (int ni = 0; ni < 2; ++ni)
          atomicAdd(&op[ni * 16], wgt * acc[mi][ni][rr]);
      }
    }
  }
}

extern "C" void kernel_launch(void* const* d_in, const int* in_sizes, int n_in,
                              void* d_out, int out_size, void* d_ws, size_t ws_size,
                              hipStream_t stream) {
  const float* x  = (const float*)d_in[0];
  const float* Wg = (const float*)d_in[1];
  const float* W1 = (const float*)d_in[2];
  const float* W3 = (const float*)d_in[3];
  const float* W2 = (const float*)d_in[4];
  float* out = (float*)d_out;

  char* ws = (char*)d_ws;
  int* counts  = (int*)(ws + OFF_CNT);
  int* list    = (int*)(ws + OFF_LIST);
  float* wpair = (float*)(ws + OFF_WP);

  hipMemsetAsync(counts, 0, 64, stream);

  if (ws_size >= WS_NEED) {
    __bf16* xb   = (__bf16*)(ws + OFF_XB);
    __bf16* Hbuf = (__bf16*)(ws + OFF_H2);
    __bf16* Obuf = (__bf16*)(ws + OFF_OB);

    gate_kernel<<<NTOK, 64, 0, stream>>>(x, Wg, counts, list, wpair, xb);

    up6_kernel<<<dim3(HID / 128, CAP / 128, NE), 256, 0, stream>>>(
        xb, W1, W3, counts, list, wpair, Hbuf);

    down7_kernel<<<dim3(DIM / 128, CAP / 128, NE), 256, 0, stream>>>(
        Hbuf, W2, counts, list, Obuf);

    combine_kernel<<<NTOK * DIM / 2048, 256, 0, stream>>>(Obuf, out);
  } else {
    hipMemsetAsync(d_out, 0, (size_t)out_size * sizeof(float), stream);
    __bf16* Hbuf = (__bf16*)(ws + OFF_H1);
    gate_kernel<<<NTOK, 64, 0, stream>>>(x, Wg, counts, list, wpair, nullptr);
    up_kernel<<<dim3(HID / 64, CAP / 64, NE), 256, 0, stream>>>(x, W1, W3, counts, list, Hbuf);
    down_kernel<<<dim3(DIM / 64, CAP / 64, NE), 256, 0, stream>>>(Hbuf, W2, counts, list, wpair, out);
  }
}

// Round 8
// 428.808 us; speedup vs baseline: 2.7083x; 1.4678x over previous
//
#include <hip/hip_runtime.h>
#include <hip/hip_bf16.h>

#define DIM  1024
#define HID  2816
#define NE   8
#define NTOK 4096
#define NPAIR 8192
#define CAP  8192

typedef __bf16 bf16x8 __attribute__((ext_vector_type(8)));
typedef float f32x4 __attribute__((ext_vector_type(4)));

// ---------------- workspace layout ----------------
#define OFF_CNT  0                         // 8 ints
#define OFF_LIST 1024                      // NE*CAP ints  = 256 KB
#define OFF_WP   (OFF_LIST + NE*CAP*4)     // NPAIR floats = 32 KB
// fallback path
#define OFF_H1   (OFF_WP + NPAIR*4)
// fast path (r2-proven 152 MB footprint)
#define OFF_XB   ((size_t)1 << 20)                  // 8 MB   (NTOK*DIM bf16)
#define OFF_W1B  ((size_t)10 << 20)                 // 46.14 MB; reused for W2b after up
#define OFF_W3B  ((size_t)57 << 20)                 // 46.14 MB; reused for Obuf after up
#define OFF_H2   ((size_t)106 << 20)                // 46.14 MB (NPAIR*HID bf16)
#define WS_NEED  (OFF_H2 + (size_t)NPAIR * HID * 2) // ~152 MB

#define GLB(p) ((const __attribute__((address_space(1))) void*)(p))
#define LDS(p) ((__attribute__((address_space(3))) void*)(p))

__device__ __forceinline__ bf16x8 pack8(float4 a, float4 b) {
  bf16x8 v;
  v[0] = (__bf16)a.x; v[1] = (__bf16)a.y; v[2] = (__bf16)a.z; v[3] = (__bf16)a.w;
  v[4] = (__bf16)b.x; v[5] = (__bf16)b.y; v[6] = (__bf16)b.z; v[7] = (__bf16)b.w;
  return v;
}

// ---------------- gating (+ x -> bf16 in fast path) -------------------------
__global__ __launch_bounds__(64) void gate_kernel(
    const float* __restrict__ x, const float* __restrict__ Wg,
    int* __restrict__ counts, int* __restrict__ list, float* __restrict__ wpair,
    __bf16* __restrict__ xb) {
  int t = blockIdx.x;
  int lane = threadIdx.x;
  const float* xp = x + (size_t)t * DIM;
  float xr[16];
#pragma unroll
  for (int i = 0; i < 16; ++i) xr[i] = xp[lane + 64 * i];
  if (xb) {
    __bf16* xo = xb + (size_t)t * DIM;
#pragma unroll
    for (int i = 0; i < 16; ++i) xo[lane + 64 * i] = (__bf16)xr[i];
  }
  float s[NE];
#pragma unroll
  for (int e = 0; e < NE; ++e) {
    const float* wp = Wg + e * DIM;
    float acc = 0.f;
#pragma unroll
    for (int i = 0; i < 16; ++i) acc += xr[i] * wp[lane + 64 * i];
#pragma unroll
    for (int off = 32; off >= 1; off >>= 1) acc += __shfl_xor(acc, off, 64);
    s[e] = acc;
  }
  if (lane == 0) {
    int i0 = 0; float b0 = s[0];
#pragma unroll
    for (int e = 1; e < NE; ++e) if (s[e] > b0) { b0 = s[e]; i0 = e; }
    int i1 = -1; float b1 = -1e30f;
#pragma unroll
    for (int e = 0; e < NE; ++e) if (e != i0 && s[e] > b1) { b1 = s[e]; i1 = e; }
    float e1 = __expf(b1 - b0);
    float w0 = 1.f / (1.f + e1);
    float w1 = e1 * w0;
    int s0 = atomicAdd(&counts[i0], 1);
    list[i0 * CAP + s0] = 2 * t;
    wpair[2 * t] = w0;
    int s1 = atomicAdd(&counts[i1], 1);
    list[i1 * CAP + s1] = 2 * t + 1;
    wpair[2 * t + 1] = w1;
  }
}

// ---------------- fp32 -> bf16 streaming convert ----------------------------
__global__ __launch_bounds__(256) void cvt_kernel(
    const float* __restrict__ src, __bf16* __restrict__ dst) {
  size_t i = (((size_t)blockIdx.x * 256) + threadIdx.x) * 8;
  float4 f0 = *(const float4*)(src + i);
  float4 f1 = *(const float4*)(src + i + 4);
  *(bf16x8*)(dst + i) = pack8(f0, f1);
}

// =============== fast path ==================================================
// 128x128x64 tiles, 4 waves (2Mx2N). Grid N-fastest (r2-proven).
// A (bf16 tokens, gathered): global_load_lds, DOUBLE-buffered, issued one
//   full compute-phase early (latency hidden under MFMA).
// B (bf16 weights from cvt, L3-hot): reg-staged bf16x8 loads issued a phase
//   early, ds_written swizzled after the barrier (r7-proven schedule).
// Raw s_barrier + explicit vmcnt/lgkmcnt; LDS chunk swizzle c ^= (row&7)
// on BOTH the global source and the ds_read (rule #21).

// ---------------- up8: H[p][:] = wpair * silu(x.W1^T) * (x.W3^T) ------------
__global__ __launch_bounds__(256, 2) void up8_kernel(
    const __bf16* __restrict__ xb, const __bf16* __restrict__ w1b,
    const __bf16* __restrict__ w3b, const int* __restrict__ counts,
    const int* __restrict__ list, const float* __restrict__ wpair,
    __bf16* __restrict__ Hbuf) {
  int e = blockIdx.z;
  int cnt = counts[e];
  int m0 = blockIdx.y * 128;
  if (m0 >= cnt) return;
  int h0 = blockIdx.x * 128;

  __shared__ __bf16 As[2][128 * 64];   // 32 KB (dbuf)
  __shared__ __bf16 B1s[128 * 64];     // 16 KB
  __shared__ __bf16 B3s[128 * 64];     // 16 KB

  int tid = threadIdx.x;
  int lane = tid & 63;
  int w = tid >> 6;
  int wr = w >> 1, wc = w & 1;
  int cl = lane & 15, hi = lane >> 4;

  const __bf16* asrc[4];
  {
    int cc = tid & 7;
#pragma unroll
    for (int i = 0; i < 4; ++i) {
      int r = i * 32 + (tid >> 3);
      int csel = (cc ^ (r & 7)) * 8;
      int mrow = m0 + r; if (mrow > cnt - 1) mrow = cnt - 1;
      int p = list[e * CAP + mrow];
      asrc[i] = xb + (size_t)(p >> 1) * DIM + csel;
    }
  }

  // B bf16 sources: row rb (0..127), half hb covers 32 K-cols (4 x 16B chunks)
  int rb = tid >> 1, hb = tid & 1;
  const __bf16* b1p = w1b + ((size_t)e * HID + h0 + rb) * DIM + hb * 32;
  const __bf16* b3p = w3b + ((size_t)e * HID + h0 + rb) * DIM + hb * 32;
  char* d1 = (char*)B1s + rb * 128;
  char* d3 = (char*)B3s + rb * 128;
  int dc[4];
#pragma unroll
  for (int j = 0; j < 4; ++j) dc[j] = ((hb * 4 + j) ^ (rb & 7)) * 16;

  f32x4 acc1[4][4] = {};
  f32x4 acc3[4][4] = {};
  bf16x8 r1b[4], r3b[4];

#define U8_LOADB(k0)                                                           \
  { _Pragma("unroll") for (int j = 0; j < 4; ++j) {                            \
      r1b[j] = *(const bf16x8*)(b1p + (k0) + j * 8);                           \
      r3b[j] = *(const bf16x8*)(b3p + (k0) + j * 8); } }
#define U8_WRITEB()                                                            \
  { _Pragma("unroll") for (int j = 0; j < 4; ++j) {                            \
      *(bf16x8*)(d1 + dc[j]) = r1b[j];                                         \
      *(bf16x8*)(d3 + dc[j]) = r3b[j]; } }
#define U8_ISSUEA(buf, k0)                                                     \
  { _Pragma("unroll") for (int i = 0; i < 4; ++i)                              \
      __builtin_amdgcn_global_load_lds(GLB(asrc[i] + (k0)),                    \
          LDS((char*)As[buf] + i * 4096 + tid * 16), 16, 0, 0); }
#define U8_COMPUTE(buf)                                                        \
  { _Pragma("unroll") for (int ks = 0; ks < 2; ++ks) {                         \
      int c = hi + ks * 4;                                                     \
      bf16x8 a[4], f1[4], f3[4];                                               \
      _Pragma("unroll") for (int mi = 0; mi < 4; ++mi) {                       \
        int r = wr * 64 + mi * 16 + cl;                                        \
        a[mi] = *(const bf16x8*)((const char*)As[buf] + r * 128 + ((c ^ (r & 7)) * 16)); \
      }                                                                        \
      _Pragma("unroll") for (int ni = 0; ni < 4; ++ni) {                       \
        int r = wc * 64 + ni * 16 + cl;                                        \
        int o = r * 128 + ((c ^ (r & 7)) * 16);                                \
        f1[ni] = *(const bf16x8*)((const char*)B1s + o);                       \
        f3[ni] = *(const bf16x8*)((const char*)B3s + o);                       \
      }                                                                        \
      _Pragma("unroll") for (int mi = 0; mi < 4; ++mi)                         \
        _Pragma("unroll") for (int ni = 0; ni < 4; ++ni) {                     \
          acc1[mi][ni] = __builtin_amdgcn_mfma_f32_16x16x32_bf16(a[mi], f1[ni], acc1[mi][ni], 0, 0, 0); \
          acc3[mi][ni] = __builtin_amdgcn_mfma_f32_16x16x32_bf16(a[mi], f3[ni], acc3[mi][ni], 0, 0, 0); \
        }                                                                      \
  } }

  U8_LOADB(0)
  U8_ISSUEA(0, 0)

#pragma unroll 1
  for (int kt = 0; kt < DIM / 64; ++kt) {
    int buf = kt & 1;
    asm volatile("s_waitcnt vmcnt(0)" ::: "memory");   // A_kt in LDS, B_kt regs
    asm volatile("s_barrier" ::: "memory");            // prev compute done
    U8_WRITEB()
    if (kt + 1 < DIM / 64) {
      U8_ISSUEA(buf ^ 1, (kt + 1) * 64)                // in flight over compute
      U8_LOADB((kt + 1) * 64)
    }
    asm volatile("s_waitcnt lgkmcnt(0)" ::: "memory"); // ds_write visible
    asm volatile("s_barrier" ::: "memory");
    U8_COMPUTE(buf)
  }

#pragma unroll
  for (int mi = 0; mi < 4; ++mi) {
#pragma unroll
    for (int rr = 0; rr < 4; ++rr) {
      int m = m0 + wr * 64 + mi * 16 + hi * 4 + rr;
      if (m < cnt) {
        int p = list[e * CAP + m];
        float wgt = wpair[p];
        __bf16* hp = Hbuf + (size_t)p * HID + h0 + wc * 64 + cl;
#pragma unroll
        for (int ni = 0; ni < 4; ++ni) {
          float v1 = acc1[mi][ni][rr], v3 = acc3[mi][ni][rr];
          float gv = (v1 / (1.f + __expf(-v1))) * v3 * wgt;
          hp[ni * 16] = (__bf16)gv;
        }
      }
    }
  }
}

// ---------------- down8: Obuf[p][:] = H[p] . W2b^T --------------------------
__global__ __launch_bounds__(256, 3) void down8_kernel(
    const __bf16* __restrict__ Hbuf, const __bf16* __restrict__ w2b,
    const int* __restrict__ counts, const int* __restrict__ list,
    __bf16* __restrict__ Obuf) {
  int e = blockIdx.z;
  int cnt = counts[e];
  int m0 = blockIdx.y * 128;
  if (m0 >= cnt) return;
  int d0 = blockIdx.x * 128;

  __shared__ __bf16 As[2][128 * 64];   // 32 KB
  __shared__ __bf16 B2s[128 * 64];     // 16 KB

  int tid = threadIdx.x;
  int lane = tid & 63;
  int w = tid >> 6;
  int wr = w >> 1, wc = w & 1;
  int cl = lane & 15, hi = lane >> 4;

  const __bf16* asrc[4];
  {
    int cc = tid & 7;
#pragma unroll
    for (int i = 0; i < 4; ++i) {
      int r = i * 32 + (tid >> 3);
      int csel = (cc ^ (r & 7)) * 8;
      int mrow = m0 + r; if (mrow > cnt - 1) mrow = cnt - 1;
      int p = list[e * CAP + mrow];
      asrc[i] = Hbuf + (size_t)p * HID + csel;
    }
  }

  int rb = tid >> 1, hb = tid & 1;
  const __bf16* b2p = w2b + ((size_t)e * DIM + d0 + rb) * HID + hb * 32;
  char* d2 = (char*)B2s + rb * 128;
  int dc[4];
#pragma unroll
  for (int j = 0; j < 4; ++j) dc[j] = ((hb * 4 + j) ^ (rb & 7)) * 16;

  f32x4 acc[4][4] = {};
  bf16x8 r2b[4];

#define D8_LOADB(k0)                                                           \
  { _Pragma("unroll") for (int j = 0; j < 4; ++j)                              \
      r2b[j] = *(const bf16x8*)(b2p + (k0) + j * 8); }
#define D8_WRITEB()                                                            \
  { _Pragma("unroll") for (int j = 0; j < 4; ++j)                              \
      *(bf16x8*)(d2 + dc[j]) = r2b[j]; }
#define D8_ISSUEA(buf, k0)                                                     \
  { _Pragma("unroll") for (int i = 0; i < 4; ++i)                              \
      __builtin_amdgcn_global_load_lds(GLB(asrc[i] + (k0)),                    \
          LDS((char*)As[buf] + i * 4096 + tid * 16), 16, 0, 0); }
#define D8_COMPUTE(buf)                                                        \
  { _Pragma("unroll") for (int ks = 0; ks < 2; ++ks) {                         \
      int c = hi + ks * 4;                                                     \
      bf16x8 a[4], b[4];                                                       \
      _Pragma("unroll") for (int mi = 0; mi < 4; ++mi) {                       \
        int r = wr * 64 + mi * 16 + cl;                                        \
        a[mi] = *(const bf16x8*)((const char*)As[buf] + r * 128 + ((c ^ (r & 7)) * 16)); \
      }                                                                        \
      _Pragma("unroll") for (int ni = 0; ni < 4; ++ni) {                       \
        int r = wc * 64 + ni * 16 + cl;                                        \
        b[ni] = *(const bf16x8*)((const char*)B2s + r * 128 + ((c ^ (r & 7)) * 16)); \
      }                                                                        \
      _Pragma("unroll") for (int mi = 0; mi < 4; ++mi)                         \
        _Pragma("unroll") for (int ni = 0; ni < 4; ++ni)                       \
          acc[mi][ni] = __builtin_amdgcn_mfma_f32_16x16x32_bf16(a[mi], b[ni], acc[mi][ni], 0, 0, 0); \
  } }

  D8_LOADB(0)
  D8_ISSUEA(0, 0)

#pragma unroll 1
  for (int kt = 0; kt < HID / 64; ++kt) {
    int buf = kt & 1;
    asm volatile("s_waitcnt vmcnt(0)" ::: "memory");
    asm volatile("s_barrier" ::: "memory");
    D8_WRITEB()
    if (kt + 1 < HID / 64) {
      D8_ISSUEA(buf ^ 1, (kt + 1) * 64)
      D8_LOADB((kt + 1) * 64)
    }
    asm volatile("s_waitcnt lgkmcnt(0)" ::: "memory");
    asm volatile("s_barrier" ::: "memory");
    D8_COMPUTE(buf)
  }

#pragma unroll
  for (int mi = 0; mi < 4; ++mi) {
#pragma unroll
    for (int rr = 0; rr < 4; ++rr) {
      int m = m0 + wr * 64 + mi * 16 + hi * 4 + rr;
      if (m < cnt) {
        int p = list[e * CAP + m];
        __bf16* op = Obuf + (size_t)p * DIM + d0 + wc * 64 + cl;
#pragma unroll
        for (int ni = 0; ni < 4; ++ni)
          op[ni * 16] = (__bf16)acc[mi][ni][rr];
      }
    }
  }
}

// ---------------- combine: out[t] = Obuf[2t] + Obuf[2t+1] -------------------
__global__ __launch_bounds__(256) void combine_kernel(
    const __bf16* __restrict__ Obuf, float* __restrict__ out) {
  size_t j = (((size_t)blockIdx.x * 256) + threadIdx.x) * 8;
  size_t t = j >> 10;
  bf16x8 a = *(const bf16x8*)(Obuf + j + t * DIM);
  bf16x8 b = *(const bf16x8*)(Obuf + j + t * DIM + DIM);
  float4 o0, o1;
  o0.x = (float)a[0] + (float)b[0]; o0.y = (float)a[1] + (float)b[1];
  o0.z = (float)a[2] + (float)b[2]; o0.w = (float)a[3] + (float)b[3];
  o1.x = (float)a[4] + (float)b[4]; o1.y = (float)a[5] + (float)b[5];
  o1.z = (float)a[6] + (float)b[6]; o1.w = (float)a[7] + (float)b[7];
  *(float4*)(out + j) = o0;
  *(float4*)(out + j + 4) = o1;
}

// =============== fallback path (round-1 kernels) ============================
__device__ __forceinline__ void cvt_store16(__bf16* dst, const float* src) {
#pragma unroll
  for (int j = 0; j < 2; ++j) {
    float4 f0 = *(const float4*)(src + j * 8);
    float4 f1 = *(const float4*)(src + j * 8 + 4);
    *(bf16x8*)(dst + j * 8) = pack8(f0, f1);
  }
}

__global__ __launch_bounds__(256) void up_kernel(
    const float* __restrict__ x, const float* __restrict__ W1,
    const float* __restrict__ W3, const int* __restrict__ counts,
    const int* __restrict__ list, __bf16* __restrict__ Hbuf) {
  int e = blockIdx.z;
  int cnt = counts[e];
  int m0 = blockIdx.y * 64;
  if (m0 >= cnt) return;
  int h0 = blockIdx.x * 64;

  __shared__ __bf16 As[64][72];
  __shared__ __bf16 B1s[64][72];
  __shared__ __bf16 B3s[64][72];

  int tid = threadIdx.x;
  int r = tid >> 2;
  int cs = (tid & 3) * 16;

  const float* asrc = nullptr;
  int mrow = m0 + r;
  if (mrow < cnt) {
    int p = list[e * CAP + mrow];
    asrc = x + (size_t)(p >> 1) * DIM;
  }
  const float* b1src = W1 + ((size_t)e * HID + (h0 + r)) * DIM;
  const float* b3src = W3 + ((size_t)e * HID + (h0 + r)) * DIM;

  int lane = tid & 63;
  int w = tid >> 6;
  int wr = w >> 1, wc = w & 1;
  int cl = lane & 15, hi = lane >> 4;

  f32x4 acc1[2][2] = {};
  f32x4 acc3[2][2] = {};

  for (int k0 = 0; k0 < DIM; k0 += 64) {
    if (asrc) {
      cvt_store16(&As[r][cs], asrc + k0 + cs);
    } else {
      bf16x8 z = {};
      *(bf16x8*)&As[r][cs] = z;
      *(bf16x8*)&As[r][cs + 8] = z;
    }
    cvt_store16(&B1s[r][cs], b1src + k0 + cs);
    cvt_store16(&B3s[r][cs], b3src + k0 + cs);
    __syncthreads();
#pragma unroll
    for (int ks = 0; ks < 64; ks += 32) {
      bf16x8 a[2], b1f[2], b3f[2];
#pragma unroll
      for (int mi = 0; mi < 2; ++mi)
        a[mi] = *(const bf16x8*)&As[wr * 32 + mi * 16 + cl][ks + hi * 8];
#pragma unroll
      for (int ni = 0; ni < 2; ++ni) {
        b1f[ni] = *(const bf16x8*)&B1s[wc * 32 + ni * 16 + cl][ks + hi * 8];
        b3f[ni] = *(const bf16x8*)&B3s[wc * 32 + ni * 16 + cl][ks + hi * 8];
      }
#pragma unroll
      for (int mi = 0; mi < 2; ++mi)
#pragma unroll
        for (int ni = 0; ni < 2; ++ni) {
          acc1[mi][ni] = __builtin_amdgcn_mfma_f32_16x16x32_bf16(a[mi], b1f[ni], acc1[mi][ni], 0, 0, 0);
          acc3[mi][ni] = __builtin_amdgcn_mfma_f32_16x16x32_bf16(a[mi], b3f[ni], acc3[mi][ni], 0, 0, 0);
        }
    }
    __syncthreads();
  }

#pragma unroll
  for (int mi = 0; mi < 2; ++mi) {
#pragma unroll
    for (int rr = 0; rr < 4; ++rr) {
      int m = m0 + wr * 32 + mi * 16 + hi * 4 + rr;
      if (m < cnt) {
        int p = list[e * CAP + m];
        __bf16* hp = Hbuf + (size_t)p * HID + h0 + wc * 32 + cl;
#pragma unroll
        for (int ni = 0; ni < 2; ++ni) {
          float v1 = acc1[mi][ni][rr], v3 = acc3[mi][ni][rr];
          float gg = (v1 / (1.f + __expf(-v1))) * v3;
          hp[ni * 16] = (__bf16)gg;
        }
      }
    }
  }
}

__global__ __launch_bounds__(256) void down_kernel(
    const __bf16* __restrict__ Hbuf, const float* __restrict__ W2,
    const int* __restrict__ counts, const int* __restrict__ list,
    const float* __restrict__ wpair, float* __restrict__ out) {
  int e = blockIdx.z;
  int cnt = counts[e];
  int m0 = blockIdx.y * 64;
  if (m0 >= cnt) return;
  int d0 = blockIdx.x * 64;

  __shared__ __bf16 As[64][72];
  __shared__ __bf16 Bs[64][72];

  int tid = threadIdx.x;
  int r = tid >> 2;
  int cs = (tid & 3) * 16;

  const __bf16* asrc = nullptr;
  int mrow = m0 + r;
  if (mrow < cnt) {
    int p = list[e * CAP + mrow];
    asrc = Hbuf + (size_t)p * HID;
  }
  const float* bsrc = W2 + ((size_t)e * DIM + (d0 + r)) * HID;

  int lane = tid & 63;
  int w = tid >> 6;
  int wr = w >> 1, wc = w & 1;
  int cl = lane & 15, hi = lane >> 4;

  f32x4 acc[2][2] = {};

  for (int k0 = 0; k0 < HID; k0 += 64) {
    if (asrc) {
      *(bf16x8*)&As[r][cs]     = *(const bf16x8*)(asrc + k0 + cs);
      *(bf16x8*)&As[r][cs + 8] = *(const bf16x8*)(asrc + k0 + cs + 8);
    } else {
      bf16x8 z = {};
      *(bf16x8*)&As[r][cs] = z;
      *(bf16x8*)&As[r][cs + 8] = z;
    }
    cvt_store16(&Bs[r][cs], bsrc + k0 + cs);
    __syncthreads();
#pragma unroll
    for (int ks = 0; ks < 64; ks += 32) {
      bf16x8 a[2], b[2];
#pragma unroll
      for (int mi = 0; mi < 2; ++mi)
        a[mi] = *(const bf16x8*)&As[wr * 32 + mi * 16 + cl][ks + hi * 8];
#pragma unroll
      for (int ni = 0; ni < 2; ++ni)
        b[ni] = *(const bf16x8*)&Bs[wc * 32 + ni * 16 + cl][ks + hi * 8];
#pragma unroll
      for (int mi = 0; mi < 2; ++mi)
#pragma unroll
        for (int ni = 0; ni < 2; ++ni)
          acc[mi][ni] = __builtin_amdgcn_mfma_f32_16x16x32_bf16(a[mi], b[ni], acc[mi][ni], 0, 0, 0);
    }
    __syncthreads();
  }

#pragma unroll
  for (int mi = 0; mi < 2; ++mi) {
#pragma unroll
    for (int rr = 0; rr < 4; ++rr) {
      int m = m0 + wr * 32 + mi * 16 + hi * 4 + rr;
      if (m < cnt) {
        int p = list[e * CAP + m];
        int t = p >> 1;
        float wgt = wpair[p];
        float* op = out + (size_t)t * DIM + d0 + wc * 32 + cl;
#pragma unroll
        for (int ni = 0; ni < 2; ++ni)
          atomicAdd(&op[ni * 16], wgt * acc[mi][ni][rr]);
      }
    }
  }
}

extern "C" void kernel_launch(void* const* d_in, const int* in_sizes, int n_in,
                              void* d_out, int out_size, void* d_ws, size_t ws_size,
                              hipStream_t stream) {
  const float* x  = (const float*)d_in[0];
  const float* Wg = (const float*)d_in[1];
  const float* W1 = (const float*)d_in[2];
  const float* W3 = (const float*)d_in[3];
  const float* W2 = (const float*)d_in[4];
  float* out = (float*)d_out;

  char* ws = (char*)d_ws;
  int* counts  = (int*)(ws + OFF_CNT);
  int* list    = (int*)(ws + OFF_LIST);
  float* wpair = (float*)(ws + OFF_WP);

  hipMemsetAsync(counts, 0, 64, stream);

  if (ws_size >= WS_NEED) {
    __bf16* xb   = (__bf16*)(ws + OFF_XB);
    __bf16* w1b  = (__bf16*)(ws + OFF_W1B);   // reused for W2b after up
    __bf16* w3b  = (__bf16*)(ws + OFF_W3B);   // reused for Obuf after up
    __bf16* Hbuf = (__bf16*)(ws + OFF_H2);
    __bf16* Obuf = (__bf16*)(ws + OFF_W3B);

    gate_kernel<<<NTOK, 64, 0, stream>>>(x, Wg, counts, list, wpair, xb);

    cvt_kernel<<<NE * HID * DIM / 2048, 256, 0, stream>>>(W1, w1b);
    cvt_kernel<<<NE * HID * DIM / 2048, 256, 0, stream>>>(W3, w3b);

    up8_kernel<<<dim3(HID / 128, CAP / 128, NE), 256, 0, stream>>>(
        xb, w1b, w3b, counts, list, wpair, Hbuf);

    cvt_kernel<<<NE * DIM * HID / 2048, 256, 0, stream>>>(W2, w1b);

    down8_kernel<<<dim3(DIM / 128, CAP / 128, NE), 256, 0, stream>>>(
        Hbuf, w1b, counts, list, Obuf);

    combine_kernel<<<NTOK * DIM / 2048, 256, 0, stream>>>(Obuf, out);
  } else {
    hipMemsetAsync(d_out, 0, (size_t)out_size * sizeof(float), stream);
    __bf16* Hbuf = (__bf16*)(ws + OFF_H1);
    gate_kernel<<<NTOK, 64, 0, stream>>>(x, Wg, counts, list, wpair, nullptr);
    up_kernel<<<dim3(HID / 64, CAP / 64, NE), 256, 0, stream>>>(x, W1, W3, counts, list, Hbuf);
    down_kernel<<<dim3(DIM / 64, CAP / 64, NE), 256, 0, stream>>>(Hbuf, W2, counts, list, wpair, out);
  }
}

// Round 9
// 377.040 us; speedup vs baseline: 3.0801x; 1.1373x over previous
//
#include <hip/hip_runtime.h>
#include <hip/hip_bf16.h>

#define DIM  1024
#define HID  2816
#define NE   8
#define NTOK 4096
#define NPAIR 8192
#define CAP  8192

#define NT_DN (DIM / 128)           // 8 N-tiles (down)
#define MT    (CAP / 128)           // 64 M-tiles
#define NWG_DN (NE * NT_DN * MT)    // 4096

typedef __bf16 bf16x8 __attribute__((ext_vector_type(8)));
typedef float f32x4 __attribute__((ext_vector_type(4)));

// ---------------- workspace layout (r2/r4-proven) ----------------
#define OFF_CNT  0                         // 8 ints
#define OFF_LIST 1024                      // NE*CAP ints  = 256 KB
#define OFF_WP   (OFF_LIST + NE*CAP*4)     // NPAIR floats = 32 KB
// fallback path
#define OFF_H1   (OFF_WP + NPAIR*4)
// fast path
#define OFF_XB   ((size_t)1 << 20)                  // 8 MB   (NTOK*DIM bf16)
#define OFF_W1B  ((size_t)10 << 20)                 // 46.14 MB; reused for W2b after up
#define OFF_W3B  ((size_t)57 << 20)                 // 46.14 MB; reused for Obuf after up
#define OFF_H2   ((size_t)106 << 20)                // 46.14 MB (NPAIR*HID bf16)
#define WS_NEED  (OFF_H2 + (size_t)NPAIR * HID * 2) // ~152 MB

#define GLB(p) ((const __attribute__((address_space(1))) void*)(p))
#define LDS(p) ((__attribute__((address_space(3))) void*)(p))

__device__ __forceinline__ bf16x8 pack8(float4 a, float4 b) {
  bf16x8 v;
  v[0] = (__bf16)a.x; v[1] = (__bf16)a.y; v[2] = (__bf16)a.z; v[3] = (__bf16)a.w;
  v[4] = (__bf16)b.x; v[5] = (__bf16)b.y; v[6] = (__bf16)b.z; v[7] = (__bf16)b.w;
  return v;
}

// ---------------- gating (+ x -> bf16 in fast path) -------------------------
__global__ __launch_bounds__(64) void gate_kernel(
    const float* __restrict__ x, const float* __restrict__ Wg,
    int* __restrict__ counts, int* __restrict__ list, float* __restrict__ wpair,
    __bf16* __restrict__ xb) {
  int t = blockIdx.x;
  int lane = threadIdx.x;
  const float* xp = x + (size_t)t * DIM;
  float xr[16];
#pragma unroll
  for (int i = 0; i < 16; ++i) xr[i] = xp[lane + 64 * i];
  if (xb) {
    __bf16* xo = xb + (size_t)t * DIM;
#pragma unroll
    for (int i = 0; i < 16; ++i) xo[lane + 64 * i] = (__bf16)xr[i];
  }
  float s[NE];
#pragma unroll
  for (int e = 0; e < NE; ++e) {
    const float* wp = Wg + e * DIM;
    float acc = 0.f;
#pragma unroll
    for (int i = 0; i < 16; ++i) acc += xr[i] * wp[lane + 64 * i];
#pragma unroll
    for (int off = 32; off >= 1; off >>= 1) acc += __shfl_xor(acc, off, 64);
    s[e] = acc;
  }
  if (lane == 0) {
    int i0 = 0; float b0 = s[0];
#pragma unroll
    for (int e = 1; e < NE; ++e) if (s[e] > b0) { b0 = s[e]; i0 = e; }
    int i1 = -1; float b1 = -1e30f;
#pragma unroll
    for (int e = 0; e < NE; ++e) if (e != i0 && s[e] > b1) { b1 = s[e]; i1 = e; }
    float e1 = __expf(b1 - b0);
    float w0 = 1.f / (1.f + e1);
    float w1 = e1 * w0;
    int s0 = atomicAdd(&counts[i0], 1);
    list[i0 * CAP + s0] = 2 * t;
    wpair[2 * t] = w0;
    int s1 = atomicAdd(&counts[i1], 1);
    list[i1 * CAP + s1] = 2 * t + 1;
    wpair[2 * t + 1] = w1;
  }
}

// ---------------- fp32 -> bf16 streaming convert ----------------------------
__global__ __launch_bounds__(256) void cvt_kernel(
    const float* __restrict__ src, __bf16* __restrict__ dst) {
  size_t i = (((size_t)blockIdx.x * 256) + threadIdx.x) * 8;
  float4 f0 = *(const float4*)(src + i);
  float4 f1 = *(const float4*)(src + i + 4);
  *(bf16x8*)(dst + i) = pack8(f0, f1);
}

// =============== up9: r2's up2 verbatim (147 us measured) ===================
// 128x128x64, 4 waves, single-buffered LDS, global_load_lds width=16,
// both-sides XOR chunk swizzle (c ^= row&7), 3D grid N-fastest.
// wpair folded into the H epilogue (linearity) so down needs no weights.
__global__ __launch_bounds__(256, 2) void up9_kernel(
    const __bf16* __restrict__ xb, const __bf16* __restrict__ w1b,
    const __bf16* __restrict__ w3b, const int* __restrict__ counts,
    const int* __restrict__ list, const float* __restrict__ wpair,
    __bf16* __restrict__ Hbuf) {
  int e = blockIdx.z;
  int cnt = counts[e];
  int m0 = blockIdx.y * 128;
  if (m0 >= cnt) return;
  int h0 = blockIdx.x * 128;

  __shared__ __bf16 As[128 * 64];
  __shared__ __bf16 B1s[128 * 64];
  __shared__ __bf16 B3s[128 * 64];

  int tid = threadIdx.x;
  int lane = tid & 63;
  int w = tid >> 6;
  int cl = lane & 15, hi = lane >> 4;
  int wr = w >> 1, wc = w & 1;
  int l8 = lane >> 3, cc = lane & 7;

  const __bf16* asrc[4];
  const __bf16* b1src[4];
  const __bf16* b3src[4];
#pragma unroll
  for (int i = 0; i < 4; ++i) {
    int r = (w * 4 + i) * 8 + l8;
    int csel = (cc ^ (r & 7)) * 8;
    int mrow = m0 + r; if (mrow > cnt - 1) mrow = cnt - 1;
    int p = list[e * CAP + mrow];
    asrc[i]  = xb + (size_t)(p >> 1) * DIM + csel;
    b1src[i] = w1b + ((size_t)e * HID + h0 + r) * DIM + csel;
    b3src[i] = w3b + ((size_t)e * HID + h0 + r) * DIM + csel;
  }

  f32x4 acc1[4][4] = {};
  f32x4 acc3[4][4] = {};

  for (int k0 = 0; k0 < DIM; k0 += 64) {
#pragma unroll
    for (int i = 0; i < 4; ++i) {
      int q = (w * 4 + i) * 1024;
      __builtin_amdgcn_global_load_lds(GLB(asrc[i] + k0),  LDS((char*)As  + q), 16, 0, 0);
      __builtin_amdgcn_global_load_lds(GLB(b1src[i] + k0), LDS((char*)B1s + q), 16, 0, 0);
      __builtin_amdgcn_global_load_lds(GLB(b3src[i] + k0), LDS((char*)B3s + q), 16, 0, 0);
    }
    __syncthreads();
#pragma unroll
    for (int ks = 0; ks < 2; ++ks) {
      int c = hi + ks * 4;
      bf16x8 a[4], bb1[4], bb3[4];
#pragma unroll
      for (int mi = 0; mi < 4; ++mi) {
        int r = wr * 64 + mi * 16 + cl;
        a[mi] = *(const bf16x8*)((const char*)As + r * 128 + ((c ^ (r & 7)) * 16));
      }
#pragma unroll
      for (int ni = 0; ni < 4; ++ni) {
        int r = wc * 64 + ni * 16 + cl;
        bb1[ni] = *(const bf16x8*)((const char*)B1s + r * 128 + ((c ^ (r & 7)) * 16));
        bb3[ni] = *(const bf16x8*)((const char*)B3s + r * 128 + ((c ^ (r & 7)) * 16));
      }
#pragma unroll
      for (int mi = 0; mi < 4; ++mi)
#pragma unroll
        for (int ni = 0; ni < 4; ++ni) {
          acc1[mi][ni] = __builtin_amdgcn_mfma_f32_16x16x32_bf16(a[mi], bb1[ni], acc1[mi][ni], 0, 0, 0);
          acc3[mi][ni] = __builtin_amdgcn_mfma_f32_16x16x32_bf16(a[mi], bb3[ni], acc3[mi][ni], 0, 0, 0);
        }
    }
    __syncthreads();
  }

#pragma unroll
  for (int mi = 0; mi < 4; ++mi) {
#pragma unroll
    for (int rr = 0; rr < 4; ++rr) {
      int m = m0 + wr * 64 + mi * 16 + hi * 4 + rr;
      if (m < cnt) {
        int p = list[e * CAP + m];
        float wgt = wpair[p];
        __bf16* hp = Hbuf + (size_t)p * HID + h0 + wc * 64 + cl;
#pragma unroll
        for (int ni = 0; ni < 4; ++ni) {
          float v1 = acc1[mi][ni][rr], v3 = acc3[mi][ni][rr];
          float gv = (v1 / (1.f + __expf(-v1))) * v3 * wgt;
          hp[ni * 16] = (__bf16)gv;
        }
      }
    }
  }
}

// =============== down9: r4's down4 verbatim (~116 us measured) ==============
// 128x128x64, 4 waves, single-buffered, 1D XCD-chunked grid M-fastest
// (consecutive blocks share the L2-resident W2b panel), plain bf16 stores.
__global__ __launch_bounds__(256, 2) void down9_kernel(
    const __bf16* __restrict__ Hbuf, const __bf16* __restrict__ w2b,
    const int* __restrict__ counts, const int* __restrict__ list,
    __bf16* __restrict__ Obuf) {
  int bid = blockIdx.x;
  int g = (bid & 7) * (NWG_DN / 8) + (bid >> 3);
  int e = g / (NT_DN * MT);
  int rr0 = g % (NT_DN * MT);
  int cnt = counts[e];
  int m0 = (rr0 % MT) * 128;
  if (m0 >= cnt) return;
  int d0 = (rr0 / MT) * 128;

  __shared__ __bf16 As[128 * 64];
  __shared__ __bf16 Bs[128 * 64];

  int tid = threadIdx.x;
  int lane = tid & 63;
  int w = tid >> 6;
  int cl = lane & 15, hi = lane >> 4;
  int wr = w >> 1, wc = w & 1;
  int l8 = lane >> 3, cc = lane & 7;

  const __bf16* asrc[4];
  const __bf16* bsrc[4];
#pragma unroll
  for (int i = 0; i < 4; ++i) {
    int r = (w * 4 + i) * 8 + l8;
    int csel = (cc ^ (r & 7)) * 8;
    int mrow = m0 + r; if (mrow > cnt - 1) mrow = cnt - 1;
    int p = list[e * CAP + mrow];
    asrc[i] = Hbuf + (size_t)p * HID + csel;
    bsrc[i] = w2b + ((size_t)e * DIM + d0 + r) * HID + csel;
  }

  f32x4 acc[4][4] = {};

  for (int k0 = 0; k0 < HID; k0 += 64) {
#pragma unroll
    for (int i = 0; i < 4; ++i) {
      int q = (w * 4 + i) * 1024;
      __builtin_amdgcn_global_load_lds(GLB(asrc[i] + k0), LDS((char*)As + q), 16, 0, 0);
      __builtin_amdgcn_global_load_lds(GLB(bsrc[i] + k0), LDS((char*)Bs + q), 16, 0, 0);
    }
    __syncthreads();
#pragma unroll
    for (int ks = 0; ks < 2; ++ks) {
      int c = hi + ks * 4;
      bf16x8 a[4], b[4];
#pragma unroll
      for (int mi = 0; mi < 4; ++mi) {
        int r = wr * 64 + mi * 16 + cl;
        a[mi] = *(const bf16x8*)((const char*)As + r * 128 + ((c ^ (r & 7)) * 16));
      }
#pragma unroll
      for (int ni = 0; ni < 4; ++ni) {
        int r = wc * 64 + ni * 16 + cl;
        b[ni] = *(const bf16x8*)((const char*)Bs + r * 128 + ((c ^ (r & 7)) * 16));
      }
#pragma unroll
      for (int mi = 0; mi < 4; ++mi)
#pragma unroll
        for (int ni = 0; ni < 4; ++ni)
          acc[mi][ni] = __builtin_amdgcn_mfma_f32_16x16x32_bf16(a[mi], b[ni], acc[mi][ni], 0, 0, 0);
    }
    __syncthreads();
  }

#pragma unroll
  for (int mi = 0; mi < 4; ++mi) {
#pragma unroll
    for (int rr = 0; rr < 4; ++rr) {
      int m = m0 + wr * 64 + mi * 16 + hi * 4 + rr;
      if (m < cnt) {
        int p = list[e * CAP + m];
        __bf16* op = Obuf + (size_t)p * DIM + d0 + wc * 64 + cl;
#pragma unroll
        for (int ni = 0; ni < 4; ++ni)
          op[ni * 16] = (__bf16)acc[mi][ni][rr];
      }
    }
  }
}

// ---------------- combine: out[t] = Obuf[2t] + Obuf[2t+1] -------------------
__global__ __launch_bounds__(256) void combine_kernel(
    const __bf16* __restrict__ Obuf, float* __restrict__ out) {
  size_t j = (((size_t)blockIdx.x * 256) + threadIdx.x) * 8;
  size_t t = j >> 10;
  bf16x8 a = *(const bf16x8*)(Obuf + j + t * DIM);
  bf16x8 b = *(const bf16x8*)(Obuf + j + t * DIM + DIM);
  float4 o0, o1;
  o0.x = (float)a[0] + (float)b[0]; o0.y = (float)a[1] + (float)b[1];
  o0.z = (float)a[2] + (float)b[2]; o0.w = (float)a[3] + (float)b[3];
  o1.x = (float)a[4] + (float)b[4]; o1.y = (float)a[5] + (float)b[5];
  o1.z = (float)a[6] + (float)b[6]; o1.w = (float)a[7] + (float)b[7];
  *(float4*)(out + j) = o0;
  *(float4*)(out + j + 4) = o1;
}

// =============== fallback path (round-1 kernels) ============================
__device__ __forceinline__ void cvt_store16(__bf16* dst, const float* src) {
#pragma unroll
  for (int j = 0; j < 2; ++j) {
    float4 f0 = *(const float4*)(src + j * 8);
    float4 f1 = *(const float4*)(src + j * 8 + 4);
    *(bf16x8*)(dst + j * 8) = pack8(f0, f1);
  }
}

__global__ __launch_bounds__(256) void up_kernel(
    const float* __restrict__ x, const float* __restrict__ W1,
    const float* __restrict__ W3, const int* __restrict__ counts,
    const int* __restrict__ list, __bf16* __restrict__ Hbuf) {
  int e = blockIdx.z;
  int cnt = counts[e];
  int m0 = blockIdx.y * 64;
  if (m0 >= cnt) return;
  int h0 = blockIdx.x * 64;

  __shared__ __bf16 As[64][72];
  __shared__ __bf16 B1s[64][72];
  __shared__ __bf16 B3s[64][72];

  int tid = threadIdx.x;
  int r = tid >> 2;
  int cs = (tid & 3) * 16;

  const float* asrc = nullptr;
  int mrow = m0 + r;
  if (mrow < cnt) {
    int p = list[e * CAP + mrow];
    asrc = x + (size_t)(p >> 1) * DIM;
  }
  const float* b1src = W1 + ((size_t)e * HID + (h0 + r)) * DIM;
  const float* b3src = W3 + ((size_t)e * HID + (h0 + r)) * DIM;

  int lane = tid & 63;
  int w = tid >> 6;
  int wr = w >> 1, wc = w & 1;
  int cl = lane & 15, hi = lane >> 4;

  f32x4 acc1[2][2] = {};
  f32x4 acc3[2][2] = {};

  for (int k0 = 0; k0 < DIM; k0 += 64) {
    if (asrc) {
      cvt_store16(&As[r][cs], asrc + k0 + cs);
    } else {
      bf16x8 z = {};
      *(bf16x8*)&As[r][cs] = z;
      *(bf16x8*)&As[r][cs + 8] = z;
    }
    cvt_store16(&B1s[r][cs], b1src + k0 + cs);
    cvt_store16(&B3s[r][cs], b3src + k0 + cs);
    __syncthreads();
#pragma unroll
    for (int ks = 0; ks < 64; ks += 32) {
      bf16x8 a[2], b1f[2], b3f[2];
#pragma unroll
      for (int mi = 0; mi < 2; ++mi)
        a[mi] = *(const bf16x8*)&As[wr * 32 + mi * 16 + cl][ks + hi * 8];
#pragma unroll
      for (int ni = 0; ni < 2; ++ni) {
        b1f[ni] = *(const bf16x8*)&B1s[wc * 32 + ni * 16 + cl][ks + hi * 8];
        b3f[ni] = *(const bf16x8*)&B3s[wc * 32 + ni * 16 + cl][ks + hi * 8];
      }
#pragma unroll
      for (int mi = 0; mi < 2; ++mi)
#pragma unroll
        for (int ni = 0; ni < 2; ++ni) {
          acc1[mi][ni] = __builtin_amdgcn_mfma_f32_16x16x32_bf16(a[mi], b1f[ni], acc1[mi][ni], 0, 0, 0);
          acc3[mi][ni] = __builtin_amdgcn_mfma_f32_16x16x32_bf16(a[mi], b3f[ni], acc3[mi][ni], 0, 0, 0);
        }
    }
    __syncthreads();
  }

#pragma unroll
  for (int mi = 0; mi < 2; ++mi) {
#pragma unroll
    for (int rr = 0; rr < 4; ++rr) {
      int m = m0 + wr * 32 + mi * 16 + hi * 4 + rr;
      if (m < cnt) {
        int p = list[e * CAP + m];
        __bf16* hp = Hbuf + (size_t)p * HID + h0 + wc * 32 + cl;
#pragma unroll
        for (int ni = 0; ni < 2; ++ni) {
          float v1 = acc1[mi][ni][rr], v3 = acc3[mi][ni][rr];
          float gg = (v1 / (1.f + __expf(-v1))) * v3;
          hp[ni * 16] = (__bf16)gg;
        }
      }
    }
  }
}

__global__ __launch_bounds__(256) void down_kernel(
    const __bf16* __restrict__ Hbuf, const float* __restrict__ W2,
    const int* __restrict__ counts, const int* __restrict__ list,
    const float* __restrict__ wpair, float* __restrict__ out) {
  int e = blockIdx.z;
  int cnt = counts[e];
  int m0 = blockIdx.y * 64;
  if (m0 >= cnt) return;
  int d0 = blockIdx.x * 64;

  __shared__ __bf16 As[64][72];
  __shared__ __bf16 Bs[64][72];

  int tid = threadIdx.x;
  int r = tid >> 2;
  int cs = (tid & 3) * 16;

  const __bf16* asrc = nullptr;
  int mrow = m0 + r;
  if (mrow < cnt) {
    int p = list[e * CAP + mrow];
    asrc = Hbuf + (size_t)p * HID;
  }
  const float* bsrc = W2 + ((size_t)e * DIM + (d0 + r)) * HID;

  int lane = tid & 63;
  int w = tid >> 6;
  int wr = w >> 1, wc = w & 1;
  int cl = lane & 15, hi = lane >> 4;

  f32x4 acc[2][2] = {};

  for (int k0 = 0; k0 < HID; k0 += 64) {
    if (asrc) {
      *(bf16x8*)&As[r][cs]     = *(const bf16x8*)(asrc + k0 + cs);
      *(bf16x8*)&As[r][cs + 8] = *(const bf16x8*)(asrc + k0 + cs + 8);
    } else {
      bf16x8 z = {};
      *(bf16x8*)&As[r][cs] = z;
      *(bf16x8*)&As[r][cs + 8] = z;
    }
    cvt_store16(&Bs[r][cs], bsrc + k0 + cs);
    __syncthreads();
#pragma unroll
    for (int ks = 0; ks < 64; ks += 32) {
      bf16x8 a[2], b[2];
#pragma unroll
      for (int mi = 0; mi < 2; ++mi)
        a[mi] = *(const bf16x8*)&As[wr * 32 + mi * 16 + cl][ks + hi * 8];
#pragma unroll
      for (int ni = 0; ni < 2; ++ni)
        b[ni] = *(const bf16x8*)&Bs[wc * 32 + ni * 16 + cl][ks + hi * 8];
#pragma unroll
      for (int mi = 0; mi < 2; ++mi)
#pragma unroll
        for (int ni = 0; ni < 2; ++ni)
          acc[mi][ni] = __builtin_amdgcn_mfma_f32_16x16x32_bf16(a[mi], b[ni], acc[mi][ni], 0, 0, 0);
    }
    __syncthreads();
  }

#pragma unroll
  for (int mi = 0; mi < 2; ++mi) {
#pragma unroll
    for (int rr = 0; rr < 4; ++rr) {
      int m = m0 + wr * 32 + mi * 16 + hi * 4 + rr;
      if (m < cnt) {
        int p = list[e * CAP + m];
        int t = p >> 1;
        float wgt = wpair[p];
        float* op = out + (size_t)t * DIM + d0 + wc * 32 + cl;
#pragma unroll
        for (int ni = 0; ni < 2; ++ni)
          atomicAdd(&op[ni * 16], wgt * acc[mi][ni][rr]);
      }
    }
  }
}

extern "C" void kernel_launch(void* const* d_in, const int* in_sizes, int n_in,
                              void* d_out, int out_size, void* d_ws, size_t ws_size,
                              hipStream_t stream) {
  const float* x  = (const float*)d_in[0];
  const float* Wg = (const float*)d_in[1];
  const float* W1 = (const float*)d_in[2];
  const float* W3 = (const float*)d_in[3];
  const float* W2 = (const float*)d_in[4];
  float* out = (float*)d_out;

  char* ws = (char*)d_ws;
  int* counts  = (int*)(ws + OFF_CNT);
  int* list    = (int*)(ws + OFF_LIST);
  float* wpair = (float*)(ws + OFF_WP);

  hipMemsetAsync(counts, 0, 64, stream);

  if (ws_size >= WS_NEED) {
    __bf16* xb   = (__bf16*)(ws + OFF_XB);
    __bf16* w1b  = (__bf16*)(ws + OFF_W1B);   // reused for W2b after up
    __bf16* w3b  = (__bf16*)(ws + OFF_W3B);   // reused for Obuf after up
    __bf16* Hbuf = (__bf16*)(ws + OFF_H2);
    __bf16* Obuf = (__bf16*)(ws + OFF_W3B);

    gate_kernel<<<NTOK, 64, 0, stream>>>(x, Wg, counts, list, wpair, xb);

    cvt_kernel<<<NE * HID * DIM / 2048, 256, 0, stream>>>(W1, w1b);
    cvt_kernel<<<NE * HID * DIM / 2048, 256, 0, stream>>>(W3, w3b);

    up9_kernel<<<dim3(HID / 128, CAP / 128, NE), 256, 0, stream>>>(
        xb, w1b, w3b, counts, list, wpair, Hbuf);

    cvt_kernel<<<NE * DIM * HID / 2048, 256, 0, stream>>>(W2, w1b);

    down9_kernel<<<NWG_DN, 256, 0, stream>>>(Hbuf, w1b, counts, list, Obuf);

    combine_kernel<<<NTOK * DIM / 2048, 256, 0, stream>>>(Obuf, out);
  } else {
    hipMemsetAsync(d_out, 0, (size_t)out_size * sizeof(float), stream);
    __bf16* Hbuf = (__bf16*)(ws + OFF_H1);
    gate_kernel<<<NTOK, 64, 0, stream>>>(x, Wg, counts, list, wpair, nullptr);
    up_kernel<<<dim3(HID / 64, CAP / 64, NE), 256, 0, stream>>>(x, W1, W3, counts, list, Hbuf);
    down_kernel<<<dim3(DIM / 64, CAP / 64, NE), 256, 0, stream>>>(Hbuf, W2, counts, list, wpair, out);
  }
}